// Round 2
// 10359.039 us; speedup vs baseline: 1.8835x; 1.8835x over previous
//
#include <hip/hip_runtime.h>
#include <hip/hip_bf16.h>
#include <math.h>

#define LSEQ 2432

typedef short bf16x8 __attribute__((ext_vector_type(8)));
typedef float f32x4 __attribute__((ext_vector_type(4)));
typedef unsigned int u32;

__device__ __forceinline__ float gelu_f(float x){
  return 0.5f * x * (1.0f + erff(x * 0.70710678118654752440f));
}
__device__ __forceinline__ float sigmoid_f(float x){
  return 1.0f / (1.0f + __expf(-x));
}
__device__ __forceinline__ unsigned short f2bf(float f){
  __hip_bfloat16 h = __float2bfloat16(f);   // RNE
  return *reinterpret_cast<unsigned short*>(&h);
}
__device__ __forceinline__ float bfu2f(unsigned short s){
  union { u32 u; float f; } X; X.u = ((u32)s) << 16; return X.f;
}
// split f32 -> (hi bf16 in low16, lo bf16 in high16)
__device__ __forceinline__ u32 packsplit(float v){
  unsigned short hi = f2bf(v);
  float lo = v - bfu2f(hi);
  unsigned short ls = f2bf(lo);
  return (u32)hi | ((u32)ls << 16);
}

// ---------- pi0: (B,1,2432,200) -> (B,25,2432,8), stride (1,25), padW 24, k=49
__global__ __launch_bounds__(256) void k_pi0(const float* __restrict__ x,
    const float* __restrict__ w, const float* __restrict__ bias,
    float* __restrict__ out){
  int idx = blockIdx.x * 256 + threadIdx.x;
  int o = blockIdx.y, b = blockIdx.z;
  int r = idx >> 3, wv = idx & 7;
  const float* xr = x + ((size_t)b * 2432 + r) * 200;
  const float* wt = w + o * 49;
  float acc = bias[o];
  int start = wv * 25 - 24;
  #pragma unroll
  for (int t = 0; t < 49; ++t){
    int ix = start + t;
    if (ix >= 0 && ix < 200) acc += xr[ix] * wt[t];
  }
  out[(((size_t)b * 25 + o) * 2432 + r) * 8 + wv] = acc;
}

// ---------- group norm (groups=5 over 25 ch)
__global__ __launch_bounds__(256) void k_gn_reduce(const float* __restrict__ p, float* __restrict__ stats){
  int b = blockIdx.x / 5, g = blockIdx.x % 5;
  const float* base = p + ((size_t)b * 25 + g * 5) * 19456;
  float s = 0.f, s2 = 0.f;
  for (int i = threadIdx.x; i < 97280; i += 256){ float v = base[i]; s += v; s2 += v * v; }
  __shared__ float sh[256], sh2[256];
  int t = threadIdx.x;
  sh[t] = s; sh2[t] = s2; __syncthreads();
  for (int off = 128; off > 0; off >>= 1){
    if (t < off){ sh[t] += sh[t+off]; sh2[t] += sh2[t+off]; }
    __syncthreads();
  }
  if (t == 0){
    float m = sh[0] / 97280.f;
    float var = sh2[0] / 97280.f - m * m;
    stats[blockIdx.x * 2] = m;
    stats[blockIdx.x * 2 + 1] = rsqrtf(var + 1e-5f);
  }
}

__global__ __launch_bounds__(256) void k_gn_apply(float* __restrict__ p, const float* __restrict__ stats,
    const float* __restrict__ gw, const float* __restrict__ gb){
  size_t i = (size_t)blockIdx.x * 256 + threadIdx.x;
  int c = (int)((i / 19456) % 25);
  int b = (int)(i / 486400);
  int g = c / 5;
  float m = stats[(b*5+g)*2], istd = stats[(b*5+g)*2+1];
  float v = (p[i] - m) * istd * gw[c] + gb[c];
  p[i] = gelu_f(v);
}

// ---------- 25->25 conv k=3 along w (width 8, pad 1)
__global__ __launch_bounds__(256) void k_pconv3(const float* __restrict__ pin,
    const float* __restrict__ w, const float* __restrict__ bias, float* __restrict__ pout){
  int idx = blockIdx.x * 256 + threadIdx.x;
  int o = blockIdx.y, b = blockIdx.z;
  int r = idx >> 3, wv = idx & 7;
  const float* ib = pin + (size_t)b * 25 * 19456 + r * 8 + wv;
  const float* wo = w + o * 75;
  float acc = bias[o];
  #pragma unroll
  for (int i = 0; i < 25; ++i){
    const float* row = ib + (size_t)i * 19456;
    float w0 = wo[i*3], w1 = wo[i*3+1], w2 = wo[i*3+2];
    if (wv > 0) acc += row[-1] * w0;
    acc += row[0] * w1;
    if (wv < 7) acc += row[1] * w2;
  }
  pout[(((size_t)b*25 + o) * 2432 + r) * 8 + wv] = acc;
}

// ---------- pe[b,l,p] = p2[b, p>>3, l, p&7]
__global__ __launch_bounds__(256) void k_pe_build(const float* __restrict__ p2, float* __restrict__ pe){
  size_t i = (size_t)blockIdx.x * 256 + threadIdx.x;
  int p = (int)(i % 200);
  size_t rem = i / 200;
  int l = (int)(rem % 2432);
  int b = (int)(rem / 2432);
  pe[i] = p2[(((size_t)b*25 + (p>>3)) * 2432 + l) * 8 + (p & 7)];
}

// ---------- spec = |DFT_200(x)| / 200  (101 bins)
__global__ __launch_bounds__(256) void k_spec(const float* __restrict__ x, float* __restrict__ spec){
  __shared__ float xr[200], ct[200], st[200];
  int row = blockIdx.x;
  int t = threadIdx.x;
  if (t < 200){
    xr[t] = x[(size_t)row * 200 + t];
    float ang = -0.031415926535897932385f * t;
    ct[t] = cosf(ang); st[t] = sinf(ang);
  }
  __syncthreads();
  if (t < 101){
    float re = 0.f, im = 0.f;
    int ph = 0;
    for (int k = 0; k < 200; ++k){
      re += xr[k] * ct[ph];
      im += xr[k] * st[ph];
      ph += t; if (ph >= 200) ph -= 200;
    }
    spec[(size_t)row * 101 + t] = sqrtf(re*re + im*im) * 0.005f;
  }
}

// ---------- pe += spec @ spec_w^T + spec_b
__global__ __launch_bounds__(256) void k_spec_mm(const float* __restrict__ spec,
    const float* __restrict__ sw, const float* __restrict__ sb, float* __restrict__ pe){
  __shared__ float sr[101];
  int row = blockIdx.x;
  int t = threadIdx.x;
  if (t < 101) sr[t] = spec[(size_t)row * 101 + t];
  __syncthreads();
  if (t < 200){
    const float* wr = sw + t * 101;
    float acc = sb[t];
    for (int f = 0; f < 101; ++f) acc += sr[f] * wr[f];
    pe[(size_t)row * 200 + t] += acc;
  }
}

// ---------- pe (b,L,200) -> peT (b,200,L), 32x32 LDS tiles
__global__ __launch_bounds__(256) void k_trp(const float* __restrict__ pe, float* __restrict__ peT){
  __shared__ float ts[32][33];
  int l0 = blockIdx.x * 32, c0 = blockIdx.y * 32, b = blockIdx.z;
  int t = threadIdx.x;
  int i = t >> 5, j = t & 31;
  #pragma unroll
  for (int pass = 0; pass < 4; ++pass){
    int ii = i + pass * 8;
    int c = c0 + j;
    ts[ii][j] = (c < 200) ? pe[((size_t)b * 2432 + l0 + ii) * 200 + c] : 0.f;
  }
  __syncthreads();
  #pragma unroll
  for (int pass = 0; pass < 4; ++pass){
    int ii = i + pass * 8;
    int c = c0 + ii;
    if (c < 200) peT[((size_t)b * 200 + c) * 2432 + l0 + j] = ts[j][ii];
  }
}

// ---------- hbuild: h[b,p,c*128+j] = peT[b,p,c*128+j] + depthwise19x7 conv
__global__ __launch_bounds__(128) void k_hbuild2(const float* __restrict__ peT,
    const float* __restrict__ pw, const float* __restrict__ pb, float* __restrict__ h){
  __shared__ float T[19][136];
  __shared__ float wsh[133];
  int c = blockIdx.x, p = blockIdx.y, b = blockIdx.z;
  int tid = threadIdx.x;
  const float* pr = peT + ((size_t)b * 200 + p) * 2432;
  for (int e = tid; e < 19 * 136; e += 128){
    int a = e / 136, m = e % 136;
    int hh = c - 9 + a, ww = m - 3;
    float v = 0.f;
    if (hh >= 0 && hh < 19 && ww >= 0 && ww < 128) v = pr[hh * 128 + ww];
    T[a][m] = v;
  }
  for (int e = tid; e < 133; e += 128) wsh[e] = pw[p * 133 + e];
  __syncthreads();
  int j = tid;
  float conv = pb[p];
  #pragma unroll
  for (int a = 0; a < 19; ++a){
    #pragma unroll
    for (int tt = 0; tt < 7; ++tt) conv += T[a][j + tt] * wsh[a * 7 + tt];
  }
  float orig = T[9][j + 3];
  h[((size_t)b * 200 + p) * 2432 + c * 128 + j] = orig + conv;
}

// ---------- weight cast f32 [O][Kin] -> bf16 [O][Kpad] (zero pad)
__global__ __launch_bounds__(256) void k_wcast(const float* __restrict__ src,
    unsigned short* __restrict__ dst, int O, int Kin, int Kpad){
  size_t i = (size_t)blockIdx.x * 256 + threadIdx.x;
  if (i >= (size_t)O * Kpad) return;
  int k = (int)(i % Kpad);
  int o = (int)(i / Kpad);
  dst[i] = (k < Kin) ? f2bf(src[(size_t)o * Kin + k]) : 0;
}

// ---------- ow cast with GLU row interleave: dst row ro <- src row (ro>>1)+(ro&1)*512
__global__ __launch_bounds__(256) void k_wcast_glu(const float* __restrict__ src,
    unsigned short* __restrict__ dst){
  size_t i = (size_t)blockIdx.x * 256 + threadIdx.x;
  if (i >= (size_t)6 * 1024 * 2048) return;
  int k = (int)(i % 2048);
  size_t rem = i / 2048;
  int ro = (int)(rem % 1024);
  int blk = (int)(rem / 1024);
  int j = (ro >> 1) + (ro & 1) * 512;
  dst[i] = f2bf(src[((size_t)blk * 1024 + j) * 2048 + k]);
}

// ---------- cast+transpose f32 [b][C][L] -> bf16 [b][L][Kpad] cols [cbase, cbase+C)
__global__ __launch_bounds__(256) void k_castT(const float* __restrict__ in,
    unsigned short* __restrict__ out, int C, int Kpad, int cbase){
  __shared__ float ts[32][33];
  int l0 = blockIdx.x * 32, c0 = blockIdx.y * 32, b = blockIdx.z;
  int t = threadIdx.x;
  int i = t >> 5, j = t & 31;
  #pragma unroll
  for (int pass = 0; pass < 4; ++pass){
    int ci = c0 + i + pass * 8;
    ts[i + pass * 8][j] = (ci < C) ? in[((size_t)b * C + ci) * LSEQ + l0 + j] : 0.f;
  }
  __syncthreads();
  #pragma unroll
  for (int pass = 0; pass < 4; ++pass){
    int li = l0 + i + pass * 8;
    out[((size_t)b * LSEQ + li) * Kpad + cbase + c0 + j] = f2bf(ts[j][i + pass * 8]);
  }
}

// ---------- gate fused with cast+transpose: actT[b][l][c] = bf16(tanh(g1)*sigmoid(g2))
__global__ __launch_bounds__(256) void k_gateT(const float* __restrict__ ht,
    const float* __restrict__ a, unsigned short* __restrict__ out){
  __shared__ float ts[32][33];
  int l0 = blockIdx.x * 32, c0 = blockIdx.y * 32, b = blockIdx.z;
  int t = threadIdx.x;
  int i = t >> 5, j = t & 31;
  #pragma unroll
  for (int pass = 0; pass < 4; ++pass){
    int ci = c0 + i + pass * 8;
    size_t i1 = ((size_t)b * 512 + ci) * LSEQ + l0 + j;
    size_t i2 = ((size_t)b * 512 + ci + 256) * LSEQ + l0 + j;
    float g1 = ht[i1] + a[i1];
    float g2 = ht[i2] + a[i2];
    ts[i + pass * 8][j] = tanhf(g1) * sigmoid_f(g2);
  }
  __syncthreads();
  #pragma unroll
  for (int pass = 0; pass < 4; ++pass){
    int li = l0 + i + pass * 8;
    out[((size_t)b * LSEQ + li) * 256 + c0 + j] = f2bf(ts[j][i + pass * 8]);
  }
}

// ---------- rms inverse scale per (b,l)
__global__ __launch_bounds__(256) void k_rmsr(const float* __restrict__ hx, float* __restrict__ rinv){
  int idx = blockIdx.x * 256 + threadIdx.x;   // 19456
  int b = idx / 2432, l = idx % 2432;
  const float* p = hx + (size_t)b * 256 * LSEQ + l;
  float s = 0.f;
  #pragma unroll 8
  for (int c = 0; c < 256; ++c){ float v = p[(size_t)c * LSEQ]; s += v * v; }
  rinv[idx] = 1.0f / (sqrtf(s * (1.0f/256.0f)) + 1e-8f);
}

// ---------- bf16 MFMA GEMM.
// act: 0 none, 1 relu, 3 GLU(pair rows -> out has O/2=512 rows)
// res2 mode (sn!=nullptr): v += sn[o]*res[oi]*rinv[b*2432+l]
__global__ __launch_bounds__(256) void k_bgemm(const unsigned short* __restrict__ Wb,
    const unsigned short* __restrict__ Xb, const float* __restrict__ bias,
    const float* __restrict__ res, const float* __restrict__ sn,
    const float* __restrict__ rinv, float* __restrict__ out,
    int O, int Kpad, float alpha, float fs, int act, int accf){
  __shared__ unsigned short Ws[128 * 40];
  __shared__ unsigned short Xs[128 * 40];
  int l0 = blockIdx.x * 128, o0 = blockIdx.y * 128, b = blockIdx.z;
  int tid = threadIdx.x;
  int w = tid >> 6, lane = tid & 63;
  int ow_ = (w & 1) * 64, lw_ = (w >> 1) * 64;
  int m = lane & 15, q = (lane >> 4) & 3;
  const unsigned short* Xbb = Xb + (size_t)b * 2432 * Kpad;
  f32x4 acc[4][4] = {};
  for (int k0 = 0; k0 < Kpad; k0 += 32){
    #pragma unroll
    for (int r = 0; r < 2; ++r){
      int idx = tid + r * 256;
      int row = idx >> 2, cq = (idx & 3) * 8;
      uint4 v = make_uint4(0u, 0u, 0u, 0u);
      int o = o0 + row;
      if (o < O) v = *(const uint4*)(Wb + (size_t)o * Kpad + k0 + cq);
      *(uint4*)&Ws[row * 40 + cq] = v;
      uint4 xv = *(const uint4*)(Xbb + (size_t)(l0 + row) * Kpad + k0 + cq);
      *(uint4*)&Xs[row * 40 + cq] = xv;
    }
    __syncthreads();
    bf16x8 A[4], Bf[4];
    #pragma unroll
    for (int t = 0; t < 4; ++t) A[t] = *(const bf16x8*)&Ws[(ow_ + t * 16 + m) * 40 + q * 8];
    #pragma unroll
    for (int u = 0; u < 4; ++u) Bf[u] = *(const bf16x8*)&Xs[(lw_ + u * 16 + m) * 40 + q * 8];
    #pragma unroll
    for (int t = 0; t < 4; ++t)
      #pragma unroll
      for (int u = 0; u < 4; ++u)
        acc[t][u] = __builtin_amdgcn_mfma_f32_16x16x32_bf16(A[t], Bf[u], acc[t][u], 0, 0, 0);
    __syncthreads();
  }
  if (act == 3){
    // GLU: reordered rows; pair (even reg r, odd reg r+1); ht row = ro>>1
    #pragma unroll
    for (int t = 0; t < 4; ++t){
      #pragma unroll
      for (int u = 0; u < 4; ++u){
        int l = l0 + lw_ + u * 16 + m;
        #pragma unroll
        for (int r = 0; r < 4; r += 2){
          int ro = o0 + ow_ + t * 16 + q * 4 + r;    // even
          int j = ro >> 1;
          float v1 = acc[t][u][r]   + bias[j];
          float v2 = acc[t][u][r+1] + bias[j + 512];
          out[((size_t)b * 512 + j) * LSEQ + l] = v1 * sigmoid_f(v2);
        }
      }
    }
    return;
  }
  #pragma unroll
  for (int t = 0; t < 4; ++t){
    #pragma unroll
    for (int u = 0; u < 4; ++u){
      int l = l0 + lw_ + u * 16 + m;
      #pragma unroll
      for (int r = 0; r < 4; ++r){
        int o = o0 + ow_ + t * 16 + q * 4 + r;
        if (o >= O) continue;
        size_t oi = ((size_t)b * O + o) * LSEQ + l;
        float v = alpha * acc[t][u][r];
        if (bias) v += bias[o];
        if (res){
          if (sn) v += sn[o] * res[oi] * rinv[b * 2432 + l];
          else v += res[oi];
        }
        if (accf) v += out[oi];
        if (act == 1) v = fmaxf(v, 0.f);
        out[oi] = v * fs;
      }
    }
  }
}

// ---------- conv3: u = gelu(conv1d(hx+noise, cw(512,256,3), cb, pad1)), fp32
__global__ __launch_bounds__(256) void k_conv3(const float* __restrict__ W,
    const float* __restrict__ bias, const float* __restrict__ A,
    const float* __restrict__ Bb, float* __restrict__ U){
  __shared__ float Ws[8][3][68];
  __shared__ float Xs[8][68];
  int l0 = blockIdx.x * 64, o0 = blockIdx.y * 64, b = blockIdx.z;
  int tid = threadIdx.x;
  int tx = tid & 15, ty = tid >> 4;
  float acc[4][4] = {};
  const float* Ab = A + (size_t)b * 256 * LSEQ;
  const float* Nb = Bb + (size_t)b * 256 * LSEQ;
  for (int k0 = 0; k0 < 256; k0 += 8){
    for (int e = tid; e < 1536; e += 256){
      int oo = e / 24, qq = e % 24;
      int kk = qq / 3, t = qq % 3;
      Ws[kk][t][oo] = W[(size_t)(o0 + oo) * 768 + (k0 + kk) * 3 + t];
    }
    for (int e = tid; e < 528; e += 256){
      int kk = e / 66, mm = e % 66;
      int li = l0 - 1 + mm;
      float v = 0.f;
      if (li >= 0 && li < LSEQ){
        size_t ii = (size_t)(k0 + kk) * LSEQ + li;
        v = Ab[ii] + Nb[ii];
      }
      Xs[kk][mm] = v;
    }
    __syncthreads();
    #pragma unroll
    for (int kk = 0; kk < 8; ++kk){
      float x6[6];
      float4 xv = *(const float4*)&Xs[kk][tx * 4];
      x6[0]=xv.x; x6[1]=xv.y; x6[2]=xv.z; x6[3]=xv.w;
      x6[4]=Xs[kk][tx*4+4]; x6[5]=Xs[kk][tx*4+5];
      #pragma unroll
      for (int t = 0; t < 3; ++t){
        float4 wv = *(const float4*)&Ws[kk][t][ty * 4];
        float wa[4]={wv.x,wv.y,wv.z,wv.w};
        #pragma unroll
        for (int i = 0; i < 4; ++i)
          #pragma unroll
          for (int jj = 0; jj < 4; ++jj)
            acc[i][jj] += wa[i] * x6[jj + t];
      }
    }
    __syncthreads();
  }
  #pragma unroll
  for (int i = 0; i < 4; ++i){
    int o = o0 + ty * 4 + i;
    #pragma unroll
    for (int jj = 0; jj < 4; ++jj){
      int l = l0 + tx * 4 + jj;
      U[((size_t)b * 512 + o) * LSEQ + l] = gelu_f(acc[i][jj] + bias[o]);
    }
  }
}

// ================== S4 via MFMA (Toeplitz GEMM, split-bf16 x3) ==================
// Per (i,s): krev[h][e] = packed(hi|lo) of f(2688 - e), e in [0,2832), f(t)=k[t] for t in [0,2432) else 0.
__global__ __launch_bounds__(256) void k_krev(const float* __restrict__ ksrc, u32* __restrict__ out){
  int h = blockIdx.y;
  int e = blockIdx.x * 256 + threadIdx.x;
  if (e >= 2832) return;
  int t = 2688 - e;
  u32 vpk = 0;
  if (t >= 0 && t < 2432) vpk = packsplit(ksrc[(size_t)h * 2432 + t]);
  out[(size_t)h * 2832 + e] = vpk;
}

#define S4_SU 2464                    // u plane row stride (elements; [2432,2464) zeroed pad)
#define S4_UPLANE (8*S4_SU*2)         // 39424 B per plane
#define S4_ULO  S4_UPLANE             // u_lo plane offset
#define S4_REV  (2*S4_UPLANE)         // 78848
#define S4_TS   (S4_REV + 2856*4)     // 90272
#define S4_LDSZ (S4_TS + 4*576)       // 92576

__device__ __forceinline__ bf16x8 s4_mk(u32 a, u32 b, u32 c, u32 d){
  union { u32 u[4]; bf16x8 v; } X; X.u[0]=a; X.u[1]=b; X.u[2]=c; X.u[3]=d; return X.v;
}

#define S4_P16H(a,b) __builtin_amdgcn_perm((a),(b),0x05040100u)
#define S4_P16L(a,b) __builtin_amdgcn_perm((a),(b),0x07060302u)

// fill pipe slot SL with A frag-pair for current Wp (tile-top stream); Wp -= 32
#define S4_FILL(SL) { \
  int Wc = Wp > 0 ? Wp : 0; \
  int ib = rl + Wc; \
  u32 w0=RV[ib], w1=RV[ib+1], w2=RV[ib+2], w3=RV[ib+3], w4=RV[ib+4], w5=RV[ib+5], w6=RV[ib+6], w7=RV[ib+7]; \
  Ph[SL] = s4_mk(S4_P16H(w1,w0), S4_P16H(w3,w2), S4_P16H(w5,w4), S4_P16H(w7,w6)); \
  Pl[SL] = s4_mk(S4_P16L(w1,w0), S4_P16L(w3,w2), S4_P16L(w5,w4), S4_P16L(w7,w6)); \
  Wp -= 32; }

#define S4_MM(ph,d,BH,BL) \
  acc[d] = __builtin_amdgcn_mfma_f32_16x16x32_bf16(Ph[((ph)+5+(d))%12], BH, acc[d], 0, 0, 0); \
  acc[d] = __builtin_amdgcn_mfma_f32_16x16x32_bf16(Pl[((ph)+5+(d))%12], BH, acc[d], 0, 0, 0); \
  acc[d] = __builtin_amdgcn_mfma_f32_16x16x32_bf16(Ph[((ph)+5+(d))%12], BL, acc[d], 0, 0, 0);

// B prefetch: clamp >2400 first (A=0 beyond seq end), then j<0 -> zeroed pad at 2432.
#define S4_PHASE(ph,BC,BN) { \
  S4_FILL(((ph)+4)%12); \
  int bn = j0 - 32; bn = bn > 2400 ? 2400 : bn; bn = bn < 0 ? 2432 : bn; \
  const char* bp = LB + ubo + 2*bn; \
  Bh##BN = *(const bf16x8*)bp; \
  Bl##BN = *(const bf16x8*)(bp + S4_ULO); \
  S4_MM(ph,0,Bh##BC,Bl##BC) S4_MM(ph,1,Bh##BC,Bl##BC) S4_MM(ph,2,Bh##BC,Bl##BC) S4_MM(ph,3,Bh##BC,Bl##BC) \
  S4_MM(ph,4,Bh##BC,Bl##BC) S4_MM(ph,5,Bh##BC,Bl##BC) S4_MM(ph,6,Bh##BC,Bl##BC) S4_MM(ph,7,Bh##BC,Bl##BC) \
  j0 -= 32; }

// One workgroup (4 waves) per h. Each wave sweeps 5 chains of 8 tiles (l spaced 32)
// with a 12-slot rotating A-frag pipe (load once per K-step, shared by all 8 tiles).
// N dim = batch (8 real cols, lanes 8..15 duplicate rows; never written).
// Tail phases (j0<0) read the zeroed B pad -> contribute exactly 0.
__global__ __launch_bounds__(256, 1) void k_s4m(const u32* __restrict__ krev,
    const float* __restrict__ Dv, const float* __restrict__ u, float* __restrict__ y){
  extern __shared__ char LB[];
  ushort* UH = (ushort*)LB;
  ushort* UL = (ushort*)(LB + S4_ULO);
  u32* RV = (u32*)(LB + S4_REV);
  int h = blockIdx.x;
  int tid = threadIdx.x;
  // ---- stage u rows (b=0..7) as bf16 hi/lo planes ----
  for (int e = tid; e < 8 * 608; e += 256){
    int b = e / 608, c4 = e % 608;
    float4 v = *(const float4*)(u + ((size_t)b * 512 + h) * 2432 + c4 * 4);
    u32 p0 = packsplit(v.x), p1 = packsplit(v.y), p2 = packsplit(v.z), p3 = packsplit(v.w);
    uint2 hw, lw;
    hw.x = (p0 & 0xffffu) | (p1 << 16);
    hw.y = (p2 & 0xffffu) | (p3 << 16);
    lw.x = (p0 >> 16) | (p1 & 0xffff0000u);
    lw.y = (p2 >> 16) | (p3 & 0xffff0000u);
    *(uint2*)(LB + (size_t)b * (S4_SU*2) + c4 * 8) = hw;
    *(uint2*)(LB + S4_ULO + (size_t)b * (S4_SU*2) + c4 * 8) = lw;
  }
  // ---- zero the 32-element tail pad of every u row (both planes) ----
  if (tid < 256){
    int b = tid >> 5, i = tid & 31;
    UH[b * S4_SU + 2432 + i] = 0;
    UL[b * S4_SU + 2432 + i] = 0;
  }
  // ---- stage reversed-k (packed hi|lo dwords) with 16-dword left guard ----
  {
    const u32* kg = krev + (size_t)h * 2832;
    for (int e = tid; e < 2856; e += 256){
      u32 v = 0;
      if (e >= 16 && e < 16 + 2832) v = kg[e - 16];
      RV[e] = v;
    }
  }
  __syncthreads();

  int lane = tid & 63;
  int wid = __builtin_amdgcn_readfirstlane(tid >> 6);
  int m = lane & 15, qq = lane >> 4;
  int rl = 16 - m + 8 * qq;                       // rev element base (lane const)
  int ubo = (m & 7) * (S4_SU*2) + qq * 16;        // byte offset in u plane
  float dv = Dv[h];
  float* TSp = (float*)(LB + S4_TS + wid * 576);
  static const int GT[2][5] = {{9,6,4,2,0},{8,7,5,3,1}};

  #pragma unroll 1
  for (int c = 0; c < 5; ++c){
    int g = GT[wid >> 1][c];
    int Lb = 256 * g + ((wid & 1) << 4);
    int ltop = Lb + 224;
    int J0 = ((ltop + 15) >> 5) << 5;
    int W0 = 2688 - ltop + J0;
    int NS = (J0 >> 5) + 1;
    int nIt = (NS + 11) / 12;

    f32x4 acc[8];
    bf16x8 Ph[12], Pl[12];
    bf16x8 Bh0, Bl0, Bh1, Bl1;
    {
      f32x4 za = {0.f, 0.f, 0.f, 0.f};
      acc[0]=za; acc[1]=za; acc[2]=za; acc[3]=za; acc[4]=za; acc[5]=za; acc[6]=za; acc[7]=za;
      bf16x8 zz = s4_mk(0u,0u,0u,0u);
      Ph[5]=zz; Ph[6]=zz; Ph[7]=zz; Ph[8]=zz; Ph[9]=zz; Ph[10]=zz; Ph[11]=zz; Ph[4]=zz;
      Pl[5]=zz; Pl[6]=zz; Pl[7]=zz; Pl[8]=zz; Pl[9]=zz; Pl[10]=zz; Pl[11]=zz; Pl[4]=zz;
    }
    int Wp = W0;
    S4_FILL(0) S4_FILL(1) S4_FILL(2) S4_FILL(3)
    int j0 = J0;
    {
      int bj0 = j0 > 2400 ? 2400 : j0;
      const char* bp0 = LB + ubo + 2 * bj0;
      Bh0 = *(const bf16x8*)bp0;
      Bl0 = *(const bf16x8*)(bp0 + S4_ULO);
    }
    #pragma unroll 1
    for (int it = 0; it < nIt; ++it){
      S4_PHASE(0,0,1) S4_PHASE(1,1,0) S4_PHASE(2,0,1) S4_PHASE(3,1,0)
      S4_PHASE(4,0,1) S4_PHASE(5,1,0) S4_PHASE(6,0,1) S4_PHASE(7,1,0)
      S4_PHASE(8,0,1) S4_PHASE(9,1,0) S4_PHASE(10,0,1) S4_PHASE(11,1,0)
    }
    // ---- epilogue: per-wave LDS transpose + D skip, coalesced y write ----
    #pragma unroll
    for (int d = 0; d < 8; ++d){
      int ld = Lb + 32 * d;
      if (ld < 2432){
        if (m < 8){
          TSp[(qq*4+0)*9 + m] = acc[d][0];
          TSp[(qq*4+1)*9 + m] = acc[d][1];
          TSp[(qq*4+2)*9 + m] = acc[d][2];
          TSp[(qq*4+3)*9 + m] = acc[d][3];
        }
        __builtin_amdgcn_wave_barrier();
        #pragma unroll
        for (int p = 0; p < 2; ++p){
          int li = lane & 15, bb = (lane >> 4) + 4 * p;
          float v = TSp[li*9 + bb];
          int l = ld + li;
          float uv = bfu2f(UH[bb * S4_SU + l]) + bfu2f(UL[bb * S4_SU + l]);
          y[((size_t)bb * 512 + h) * 2432 + l] = v + dv * uv;
        }
        __builtin_amdgcn_wave_barrier();
      }
    }
  }
}

// ---------- final LayerNorm over last dim (200) with transpose
__global__ __launch_bounds__(256) void k_ln(const float* __restrict__ o2,
    const float* __restrict__ lw, const float* __restrict__ lb2, float* __restrict__ out){
  __shared__ float s1[256], s2[256];
  int row = blockIdx.x;
  int b = row / 2432, l = row % 2432;
  int t = threadIdx.x;
  float v = 0.f;
  if (t < 200) v = o2[((size_t)b * 200 + t) * LSEQ + l];
  s1[t] = v; s2[t] = v * v;
  __syncthreads();
  for (int off = 128; off > 0; off >>= 1){
    if (t < off){ s1[t] += s1[t + off]; s2[t] += s2[t + off]; }
    __syncthreads();
  }
  float m = s1[0] * 0.005f;
  float var = s2[0] * 0.005f - m * m;
  float istd = rsqrtf(var + 1e-5f);
  if (t < 200) out[(size_t)row * 200 + t] = (v - m) * istd * lw[t] + lb2[t];
}

extern "C" void kernel_launch(void* const* d_in, const int* in_sizes, int n_in,
                              void* d_out, int out_size, void* d_ws, size_t ws_size,
                              hipStream_t stream){
  const float* x     = (const float*)d_in[0];
  const float* pe_w  = (const float*)d_in[1];
  const float* pe_b  = (const float*)d_in[2];
  const float* pi0_w = (const float*)d_in[3];
  const float* pi0_b = (const float*)d_in[4];
  const float* gn0_w = (const float*)d_in[5];
  const float* gn0_b = (const float*)d_in[6];
  const float* pi1_w = (const float*)d_in[7];
  const float* pi1_b = (const float*)d_in[8];
  const float* gn1_w = (const float*)d_in[9];
  const float* gn1_b = (const float*)d_in[10];
  const float* pi2_w = (const float*)d_in[11];
  const float* pi2_b = (const float*)d_in[12];
  const float* gn2_w = (const float*)d_in[13];
  const float* gn2_b = (const float*)d_in[14];
  const float* spec_w= (const float*)d_in[15];
  const float* spec_b= (const float*)d_in[16];
  const float* ic_w  = (const float*)d_in[17];
  const float* ic_b  = (const float*)d_in[18];
  const float* blk_sn= (const float*)d_in[19];
  const float* blk_cw= (const float*)d_in[20];
  const float* blk_cb= (const float*)d_in[21];
  const float* blk_k = (const float*)d_in[22];
  const float* blk_D = (const float*)d_in[23];
  const float* blk_ow= (const float*)d_in[24];
  const float* blk_ob= (const float*)d_in[25];
  const float* blk_Wv= (const float*)d_in[26];
  const float* blk_bv= (const float*)d_in[27];
  const float* blk_Wo= (const float*)d_in[28];
  const float* blk_bo= (const float*)d_in[29];
  const float* blk_rw= (const float*)d_in[30];
  const float* blk_rb= (const float*)d_in[31];
  const float* blk_sw= (const float*)d_in[32];
  const float* blk_sb= (const float*)d_in[33];
  const float* fc_w  = (const float*)d_in[34];
  const float* fc_b  = (const float*)d_in[35];
  const float* zc_w  = (const float*)d_in[36];
  const float* zc_b  = (const float*)d_in[37];
  const float* ln_w  = (const float*)d_in[38];
  const float* ln_b  = (const float*)d_in[39];

  // allow >64KB dynamic LDS for k_s4m (host-side, graph-capture safe)
  static int s4m_attr = 0;
  if (!s4m_attr){
    hipFuncSetAttribute(reinterpret_cast<const void*>(k_s4m),
                        hipFuncAttributeMaxDynamicSharedMemorySize, S4_LDSZ);
    s4m_attr = 1;
  }

  float* Wsp = (float*)d_ws;
  const size_t NLL = (size_t)8 * 256 * 2432;    // 4,980,736 floats
  // layout (float units): total 64,602,192 floats = 258.4 MB (< proven 259 MB)
  float* noise = Wsp;                 // [0,1)
  float* hxb   = Wsp + NLL;           // [1,2)
  float* skb   = Wsp + 2 * NLL;       // [2,3)
  float* ub    = Wsp + 3 * NLL;       // [3,5)  u / v / a / fc-out
  float* ysb   = Wsp + 5 * NLL;       // [5,7)  s4-out per s / ht / zc-out
  float* htb   = ysb;
  unsigned short* actT = (unsigned short*)(Wsp + 7 * NLL);   // [7,11) bf16 [b][l][2048]
  unsigned short* wB = (unsigned short*)(Wsp + 11 * NLL);
  unsigned short* owB = wB;                    // 6*1024*2048 = 12,582,912
  unsigned short* WvB = wB + 12582912;         // 1,572,864
  unsigned short* WoB = wB + 14155776;         // 1,572,864
  unsigned short* rwB = wB + 15728640;         // 393,216
  unsigned short* swB = wB + 16121856;         // 393,216
  unsigned short* icB = wB + 16515072;         // 57,344
  unsigned short* fcB = wB + 16572416;         // 65,536
  unsigned short* zcB = wB + 16637952;         // 51,200 -> end 16,689,152 ushorts
  float* rinv   = Wsp + 11 * NLL + 8344576;    // 19,456 floats
  float* gnstats= rinv + 19456;                // 80 floats
  u32* krevB = (u32*)(Wsp + 63152208);         // 512*2832 dwords = 5.8 MB

  // front-end aliases (regions dead at that point)
  float* p0 = ub;
  float* p1 = ysb;
  float* p2 = ub;
  float* pe = Wsp + 7 * NLL;          // actT region (floats), dead before first castT use
  float* spec = Wsp + 8 * NLL;
  float* peT = skb;                   // skb garbage OK (first sw gemm accf=0)
  float* hb = hxb;                    // overwritten later by memcpy noise->hxb

  const float SQ05 = 0.70710678118654752440f;
  const float SQ16 = 0.40824829046386301637f;

  // ---- weight casts (bf16) ----
  k_wcast_glu<<<49152,256,0,stream>>>(blk_ow, owB);
  k_wcast<<<(3072*512+255)/256,256,0,stream>>>(blk_Wv, WvB, 3072, 512, 512);
  k_wcast<<<(3072*512+255)/256,256,0,stream>>>(blk_Wo, WoB, 3072, 512, 512);
  k_wcast<<<(1536*256+255)/256,256,0,stream>>>(blk_rw, rwB, 1536, 256, 256);
  k_wcast<<<(1536*256+255)/256,256,0,stream>>>(blk_sw, swB, 1536, 256, 256);
  k_wcast<<<(256*224+255)/256,256,0,stream>>>(ic_w, icB, 256, 200, 224);
  k_wcast<<<(256*256+255)/256,256,0,stream>>>(fc_w, fcB, 256, 256, 256);
  k_wcast<<<(200*256+255)/256,256,0,stream>>>(zc_w, zcB, 200, 256, 256);

  // ---- PatchEmbedding ----
  k_pi0<<<dim3(76,25,8), 256, 0, stream>>>(x, pi0_w, pi0_b, p0);
  k_gn_reduce<<<40,256,0,stream>>>(p0, gnstats);
  k_gn_apply<<<15200,256,0,stream>>>(p0, gnstats, gn0_w, gn0_b);
  k_pconv3<<<dim3(76,25,8),256,0,stream>>>(p0, pi1_w, pi1_b, p1);
  k_gn_reduce<<<40,256,0,stream>>>(p1, gnstats);
  k_gn_apply<<<15200,256,0,stream>>>(p1, gnstats, gn1_w, gn1_b);
  k_pconv3<<<dim3(76,25,8),256,0,stream>>>(p1, pi2_w, pi2_b, p2);
  k_gn_reduce<<<40,256,0,stream>>>(p2, gnstats);
  k_gn_apply<<<15200,256,0,stream>>>(p2, gnstats, gn2_w, gn2_b);
  k_pe_build<<<15200,256,0,stream>>>(p2, pe);
  k_spec<<<19456,256,0,stream>>>(x, spec);
  k_spec_mm<<<19456,256,0,stream>>>(spec, spec_w, spec_b, pe);
  k_trp<<<dim3(76,7,8),256,0,stream>>>(pe, peT);
  k_hbuild2<<<dim3(19,200,8),128,0,stream>>>(peT, pe_w, pe_b, hb);
  k_castT<<<dim3(76,7,8),256,0,stream>>>(hb, actT, 200, 224, 0);
  k_bgemm<<<dim3(19,2,8),256,0,stream>>>(icB, actT, ic_b, nullptr, nullptr, nullptr,
                                         noise, 256, 224, 1.f, 1.f, 1, 0);
  hipMemcpyAsync(hxb, noise, NLL * sizeof(float), hipMemcpyDeviceToDevice, stream);

  // ---- residual blocks ----
  for (int i = 0; i < 6; ++i){
    const float* sn = blk_sn + i * 256;
    const float* cw = blk_cw + (size_t)i * 512 * 768;
    const float* cb = blk_cb + i * 512;
    const float* ob = blk_ob + i * 1024;
    const float* bv = blk_bv + i * 512;
    const float* bo = blk_bo + i * 512;
    const float* rb = blk_rb + i * 256;
    const float* sb = blk_sb + i * 256;

    k_rmsr<<<76,256,0,stream>>>(hxb, rinv);
    k_conv3<<<dim3(38,8,8),256,0,stream>>>(cw, cb, hxb, noise, ub);
    for (int s = 0; s < 4; ++s){
      const float* kw = blk_k + ((size_t)i * 4 + s) * 512 * 2432;
      const float* Dvp = blk_D + ((size_t)i * 4 + s) * 512;
      k_krev<<<dim3(12,512),256,0,stream>>>(kw, krevB);
      k_s4m<<<dim3(512),256,S4_LDSZ,stream>>>(krevB, Dvp, ub, ysb);
      k_castT<<<dim3(76,16,8),256,0,stream>>>(ysb, actT, 512, 2048, s * 512);
    }
    // fused ow-GEMM + GLU -> ht (512 ch)
    k_bgemm<<<dim3(19,8,8),256,0,stream>>>(owB + (size_t)i*1024*2048, actT, ob,
                                           nullptr, nullptr, nullptr, htb,
                                           1024, 2048, 1.f, 1.f, 3, 0);
    k_castT<<<dim3(76,16,8),256,0,stream>>>(htb, actT, 512, 512, 0);
    k_bgemm<<<dim3(19,4,8),256,0,stream>>>(WvB + (size_t)i*512*512, actT, bv,
                                           nullptr, nullptr, nullptr, ub,
                                           512, 512, 1.f, 1.f, 0, 0);
    k_castT<<<dim3(76,16,8),256,0,stream>>>(ub, actT, 512, 512, 0);
    k_bgemm<<<dim3(19,4,8),256,0,stream>>>(WoB + (size_t)i*512*512, actT, bo,
                                           nullptr, nullptr, nullptr, ub,
                                           512, 512, 1.f, 1.f, 0, 0);
    k_gateT<<<dim3(76,8,8),256,0,stream>>>(htb, ub, actT);
    // rw-GEMM with fused RMS residual: hx = (sn*hx*rinv + rw@out + rb)*sqrt(0.5)
    k_bgemm<<<dim3(19,2,8),256,0,stream>>>(rwB + (size_t)i*256*256, actT, rb,
                                           hxb, sn, rinv, hxb,
                                           256, 256, 1.f, SQ05, 0, 0);
    k_bgemm<<<dim3(19,2,8),256,0,stream>>>(swB + (size_t)i*256*256, actT, sb,
                                           nullptr, nullptr, nullptr, skb,
                                           256, 256, 1.f, 1.f, 0, i==0?0:1);
  }

  // ---- tail ----
  k_castT<<<dim3(76,8,8),256,0,stream>>>(skb, actT, 256, 256, 0);
  k_bgemm<<<dim3(19,2,8),256,0,stream>>>(fcB, actT, fc_b, nullptr, nullptr, nullptr,
                                         ub, 256, 256, SQ16, 1.f, 1, 0);
  k_castT<<<dim3(76,8,8),256,0,stream>>>(ub, actT, 256, 256, 0);
  k_bgemm<<<dim3(19,2,8),256,0,stream>>>(zcB, actT, zc_b, nullptr, nullptr, nullptr,
                                         ysb, 200, 256, 1.f, 1.f, 0, 0);
  k_ln<<<19456,256,0,stream>>>(ysb, ln_w, ln_b, (float*)d_out);
}

// Round 3
// 9409.612 us; speedup vs baseline: 2.0735x; 1.1009x over previous
//
#include <hip/hip_runtime.h>
#include <hip/hip_bf16.h>
#include <math.h>

#define LSEQ 2432

typedef short bf16x8 __attribute__((ext_vector_type(8)));
typedef float f32x4 __attribute__((ext_vector_type(4)));
typedef unsigned int u32;

__device__ __forceinline__ float gelu_f(float x){
  return 0.5f * x * (1.0f + erff(x * 0.70710678118654752440f));
}
__device__ __forceinline__ float sigmoid_f(float x){
  return 1.0f / (1.0f + __expf(-x));
}
__device__ __forceinline__ unsigned short f2bf(float f){
  __hip_bfloat16 h = __float2bfloat16(f);   // RNE
  return *reinterpret_cast<unsigned short*>(&h);
}
__device__ __forceinline__ float bfu2f(unsigned short s){
  union { u32 u; float f; } X; X.u = ((u32)s) << 16; return X.f;
}
// split f32 -> (hi bf16 in low16, lo bf16 in high16)
__device__ __forceinline__ u32 packsplit(float v){
  unsigned short hi = f2bf(v);
  float lo = v - bfu2f(hi);
  unsigned short ls = f2bf(lo);
  return (u32)hi | ((u32)ls << 16);
}

// ---------- pi0: (B,1,2432,200) -> (B,25,2432,8), stride (1,25), padW 24, k=49
__global__ __launch_bounds__(256) void k_pi0(const float* __restrict__ x,
    const float* __restrict__ w, const float* __restrict__ bias,
    float* __restrict__ out){
  int idx = blockIdx.x * 256 + threadIdx.x;
  int o = blockIdx.y, b = blockIdx.z;
  int r = idx >> 3, wv = idx & 7;
  const float* xr = x + ((size_t)b * 2432 + r) * 200;
  const float* wt = w + o * 49;
  float acc = bias[o];
  int start = wv * 25 - 24;
  #pragma unroll
  for (int t = 0; t < 49; ++t){
    int ix = start + t;
    if (ix >= 0 && ix < 200) acc += xr[ix] * wt[t];
  }
  out[(((size_t)b * 25 + o) * 2432 + r) * 8 + wv] = acc;
}

// ---------- group norm (groups=5 over 25 ch)
__global__ __launch_bounds__(256) void k_gn_reduce(const float* __restrict__ p, float* __restrict__ stats){
  int b = blockIdx.x / 5, g = blockIdx.x % 5;
  const float* base = p + ((size_t)b * 25 + g * 5) * 19456;
  float s = 0.f, s2 = 0.f;
  for (int i = threadIdx.x; i < 97280; i += 256){ float v = base[i]; s += v; s2 += v * v; }
  __shared__ float sh[256], sh2[256];
  int t = threadIdx.x;
  sh[t] = s; sh2[t] = s2; __syncthreads();
  for (int off = 128; off > 0; off >>= 1){
    if (t < off){ sh[t] += sh[t+off]; sh2[t] += sh2[t+off]; }
    __syncthreads();
  }
  if (t == 0){
    float m = sh[0] / 97280.f;
    float var = sh2[0] / 97280.f - m * m;
    stats[blockIdx.x * 2] = m;
    stats[blockIdx.x * 2 + 1] = rsqrtf(var + 1e-5f);
  }
}

__global__ __launch_bounds__(256) void k_gn_apply(float* __restrict__ p, const float* __restrict__ stats,
    const float* __restrict__ gw, const float* __restrict__ gb){
  size_t i = (size_t)blockIdx.x * 256 + threadIdx.x;
  int c = (int)((i / 19456) % 25);
  int b = (int)(i / 486400);
  int g = c / 5;
  float m = stats[(b*5+g)*2], istd = stats[(b*5+g)*2+1];
  float v = (p[i] - m) * istd * gw[c] + gb[c];
  p[i] = gelu_f(v);
}

// ---------- 25->25 conv k=3 along w (width 8, pad 1)
__global__ __launch_bounds__(256) void k_pconv3(const float* __restrict__ pin,
    const float* __restrict__ w, const float* __restrict__ bias, float* __restrict__ pout){
  int idx = blockIdx.x * 256 + threadIdx.x;
  int o = blockIdx.y, b = blockIdx.z;
  int r = idx >> 3, wv = idx & 7;
  const float* ib = pin + (size_t)b * 25 * 19456 + r * 8 + wv;
  const float* wo = w + o * 75;
  float acc = bias[o];
  #pragma unroll
  for (int i = 0; i < 25; ++i){
    const float* row = ib + (size_t)i * 19456;
    float w0 = wo[i*3], w1 = wo[i*3+1], w2 = wo[i*3+2];
    if (wv > 0) acc += row[-1] * w0;
    acc += row[0] * w1;
    if (wv < 7) acc += row[1] * w2;
  }
  pout[(((size_t)b*25 + o) * 2432 + r) * 8 + wv] = acc;
}

// ---------- pe[b,l,p] = p2[b, p>>3, l, p&7]
__global__ __launch_bounds__(256) void k_pe_build(const float* __restrict__ p2, float* __restrict__ pe){
  size_t i = (size_t)blockIdx.x * 256 + threadIdx.x;
  int p = (int)(i % 200);
  size_t rem = i / 200;
  int l = (int)(rem % 2432);
  int b = (int)(rem / 2432);
  pe[i] = p2[(((size_t)b*25 + (p>>3)) * 2432 + l) * 8 + (p & 7)];
}

// ---------- spec = |DFT_200(x)| / 200  (101 bins)
__global__ __launch_bounds__(256) void k_spec(const float* __restrict__ x, float* __restrict__ spec){
  __shared__ float xr[200], ct[200], st[200];
  int row = blockIdx.x;
  int t = threadIdx.x;
  if (t < 200){
    xr[t] = x[(size_t)row * 200 + t];
    float ang = -0.031415926535897932385f * t;
    ct[t] = cosf(ang); st[t] = sinf(ang);
  }
  __syncthreads();
  if (t < 101){
    float re = 0.f, im = 0.f;
    int ph = 0;
    for (int k = 0; k < 200; ++k){
      re += xr[k] * ct[ph];
      im += xr[k] * st[ph];
      ph += t; if (ph >= 200) ph -= 200;
    }
    spec[(size_t)row * 101 + t] = sqrtf(re*re + im*im) * 0.005f;
  }
}

// ---------- pe += spec @ spec_w^T + spec_b
__global__ __launch_bounds__(256) void k_spec_mm(const float* __restrict__ spec,
    const float* __restrict__ sw, const float* __restrict__ sb, float* __restrict__ pe){
  __shared__ float sr[101];
  int row = blockIdx.x;
  int t = threadIdx.x;
  if (t < 101) sr[t] = spec[(size_t)row * 101 + t];
  __syncthreads();
  if (t < 200){
    const float* wr = sw + t * 101;
    float acc = sb[t];
    for (int f = 0; f < 101; ++f) acc += sr[f] * wr[f];
    pe[(size_t)row * 200 + t] += acc;
  }
}

// ---------- pe (b,L,200) -> peT (b,200,L), 32x32 LDS tiles
__global__ __launch_bounds__(256) void k_trp(const float* __restrict__ pe, float* __restrict__ peT){
  __shared__ float ts[32][33];
  int l0 = blockIdx.x * 32, c0 = blockIdx.y * 32, b = blockIdx.z;
  int t = threadIdx.x;
  int i = t >> 5, j = t & 31;
  #pragma unroll
  for (int pass = 0; pass < 4; ++pass){
    int ii = i + pass * 8;
    int c = c0 + j;
    ts[ii][j] = (c < 200) ? pe[((size_t)b * 2432 + l0 + ii) * 200 + c] : 0.f;
  }
  __syncthreads();
  #pragma unroll
  for (int pass = 0; pass < 4; ++pass){
    int ii = i + pass * 8;
    int c = c0 + ii;
    if (c < 200) peT[((size_t)b * 200 + c) * 2432 + l0 + j] = ts[j][ii];
  }
}

// ---------- hbuild: h[b,p,c*128+j] = peT[b,p,c*128+j] + depthwise19x7 conv
__global__ __launch_bounds__(128) void k_hbuild2(const float* __restrict__ peT,
    const float* __restrict__ pw, const float* __restrict__ pb, float* __restrict__ h){
  __shared__ float T[19][136];
  __shared__ float wsh[133];
  int c = blockIdx.x, p = blockIdx.y, b = blockIdx.z;
  int tid = threadIdx.x;
  const float* pr = peT + ((size_t)b * 200 + p) * 2432;
  for (int e = tid; e < 19 * 136; e += 128){
    int a = e / 136, m = e % 136;
    int hh = c - 9 + a, ww = m - 3;
    float v = 0.f;
    if (hh >= 0 && hh < 19 && ww >= 0 && ww < 128) v = pr[hh * 128 + ww];
    T[a][m] = v;
  }
  for (int e = tid; e < 133; e += 128) wsh[e] = pw[p * 133 + e];
  __syncthreads();
  int j = tid;
  float conv = pb[p];
  #pragma unroll
  for (int a = 0; a < 19; ++a){
    #pragma unroll
    for (int tt = 0; tt < 7; ++tt) conv += T[a][j + tt] * wsh[a * 7 + tt];
  }
  float orig = T[9][j + 3];
  h[((size_t)b * 200 + p) * 2432 + c * 128 + j] = orig + conv;
}

// ---------- weight cast f32 [O][Kin] -> bf16 [O][Kpad] (zero pad)
__global__ __launch_bounds__(256) void k_wcast(const float* __restrict__ src,
    unsigned short* __restrict__ dst, int O, int Kin, int Kpad){
  size_t i = (size_t)blockIdx.x * 256 + threadIdx.x;
  if (i >= (size_t)O * Kpad) return;
  int k = (int)(i % Kpad);
  int o = (int)(i / Kpad);
  dst[i] = (k < Kin) ? f2bf(src[(size_t)o * Kin + k]) : 0;
}

// ---------- ow cast with GLU row interleave: dst row ro <- src row (ro>>1)+(ro&1)*512
__global__ __launch_bounds__(256) void k_wcast_glu(const float* __restrict__ src,
    unsigned short* __restrict__ dst){
  size_t i = (size_t)blockIdx.x * 256 + threadIdx.x;
  if (i >= (size_t)6 * 1024 * 2048) return;
  int k = (int)(i % 2048);
  size_t rem = i / 2048;
  int ro = (int)(rem % 1024);
  int blk = (int)(rem / 1024);
  int j = (ro >> 1) + (ro & 1) * 512;
  dst[i] = f2bf(src[((size_t)blk * 1024 + j) * 2048 + k]);
}

// ---------- cast+transpose f32 [b][C][L] -> bf16 [b][L][Kpad] cols [cbase, cbase+C)
__global__ __launch_bounds__(256) void k_castT(const float* __restrict__ in,
    unsigned short* __restrict__ out, int C, int Kpad, int cbase){
  __shared__ float ts[32][33];
  int l0 = blockIdx.x * 32, c0 = blockIdx.y * 32, b = blockIdx.z;
  int t = threadIdx.x;
  int i = t >> 5, j = t & 31;
  #pragma unroll
  for (int pass = 0; pass < 4; ++pass){
    int ci = c0 + i + pass * 8;
    ts[i + pass * 8][j] = (ci < C) ? in[((size_t)b * C + ci) * LSEQ + l0 + j] : 0.f;
  }
  __syncthreads();
  #pragma unroll
  for (int pass = 0; pass < 4; ++pass){
    int li = l0 + i + pass * 8;
    out[((size_t)b * LSEQ + li) * Kpad + cbase + c0 + j] = f2bf(ts[j][i + pass * 8]);
  }
}

// ---------- pack+transpose (hx+noise) f32 [b][256][L] -> u32 hi|lo [b][L][256]
__global__ __launch_bounds__(256) void k_packT(const float* __restrict__ A,
    const float* __restrict__ N, u32* __restrict__ out){
  __shared__ float ts[32][33];
  int l0 = blockIdx.x * 32, c0 = blockIdx.y * 32, b = blockIdx.z;
  int t = threadIdx.x;
  int i = t >> 5, j = t & 31;
  #pragma unroll
  for (int pass = 0; pass < 4; ++pass){
    int ci = c0 + i + pass * 8;
    size_t ii = ((size_t)b * 256 + ci) * LSEQ + l0 + j;
    ts[i + pass * 8][j] = A[ii] + N[ii];
  }
  __syncthreads();
  #pragma unroll
  for (int pass = 0; pass < 4; ++pass){
    int li = l0 + i + pass * 8;
    out[((size_t)b * LSEQ + li) * 256 + c0 + j] = packsplit(ts[j][i + pass * 8]);
  }
}

// ---------- pack conv3 weights: Wp[o][t*256+c] = packsplit(cw[o][c][t])
__global__ __launch_bounds__(256) void k_wpack3(const float* __restrict__ cw, u32* __restrict__ Wp){
  int i = blockIdx.x * 256 + threadIdx.x;     // 512*768
  int o = i / 768, rem = i % 768;
  int t = rem / 256, c = rem % 256;
  Wp[i] = packsplit(cw[((size_t)o * 256 + c) * 3 + t]);
}

// ---------- gate fused with cast+transpose: actT[b][l][c] = bf16(tanh(g1)*sigmoid(g2))
__global__ __launch_bounds__(256) void k_gateT(const float* __restrict__ ht,
    const float* __restrict__ a, unsigned short* __restrict__ out){
  __shared__ float ts[32][33];
  int l0 = blockIdx.x * 32, c0 = blockIdx.y * 32, b = blockIdx.z;
  int t = threadIdx.x;
  int i = t >> 5, j = t & 31;
  #pragma unroll
  for (int pass = 0; pass < 4; ++pass){
    int ci = c0 + i + pass * 8;
    size_t i1 = ((size_t)b * 512 + ci) * LSEQ + l0 + j;
    size_t i2 = ((size_t)b * 512 + ci + 256) * LSEQ + l0 + j;
    float g1 = ht[i1] + a[i1];
    float g2 = ht[i2] + a[i2];
    ts[i + pass * 8][j] = tanhf(g1) * sigmoid_f(g2);
  }
  __syncthreads();
  #pragma unroll
  for (int pass = 0; pass < 4; ++pass){
    int li = l0 + i + pass * 8;
    out[((size_t)b * LSEQ + li) * 256 + c0 + j] = f2bf(ts[j][i + pass * 8]);
  }
}

// ---------- rms inverse scale per (b,l)
__global__ __launch_bounds__(256) void k_rmsr(const float* __restrict__ hx, float* __restrict__ rinv){
  int idx = blockIdx.x * 256 + threadIdx.x;   // 19456
  int b = idx / 2432, l = idx % 2432;
  const float* p = hx + (size_t)b * 256 * LSEQ + l;
  float s = 0.f;
  #pragma unroll 8
  for (int c = 0; c < 256; ++c){ float v = p[(size_t)c * LSEQ]; s += v * v; }
  rinv[idx] = 1.0f / (sqrtf(s * (1.0f/256.0f)) + 1e-8f);
}

// ---------- bf16 MFMA GEMM.
// act: 0 none, 1 relu, 3 GLU(pair rows -> out has O/2=512 rows)
// res2 mode (sn!=nullptr): v += sn[o]*res[oi]*rinv[b*2432+l]
__global__ __launch_bounds__(256) void k_bgemm(const unsigned short* __restrict__ Wb,
    const unsigned short* __restrict__ Xb, const float* __restrict__ bias,
    const float* __restrict__ res, const float* __restrict__ sn,
    const float* __restrict__ rinv, float* __restrict__ out,
    int O, int Kpad, float alpha, float fs, int act, int accf){
  __shared__ unsigned short Ws[128 * 40];
  __shared__ unsigned short Xs[128 * 40];
  int l0 = blockIdx.x * 128, o0 = blockIdx.y * 128, b = blockIdx.z;
  int tid = threadIdx.x;
  int w = tid >> 6, lane = tid & 63;
  int ow_ = (w & 1) * 64, lw_ = (w >> 1) * 64;
  int m = lane & 15, q = (lane >> 4) & 3;
  const unsigned short* Xbb = Xb + (size_t)b * 2432 * Kpad;
  f32x4 acc[4][4] = {};
  for (int k0 = 0; k0 < Kpad; k0 += 32){
    #pragma unroll
    for (int r = 0; r < 2; ++r){
      int idx = tid + r * 256;
      int row = idx >> 2, cq = (idx & 3) * 8;
      uint4 v = make_uint4(0u, 0u, 0u, 0u);
      int o = o0 + row;
      if (o < O) v = *(const uint4*)(Wb + (size_t)o * Kpad + k0 + cq);
      *(uint4*)&Ws[row * 40 + cq] = v;
      uint4 xv = *(const uint4*)(Xbb + (size_t)(l0 + row) * Kpad + k0 + cq);
      *(uint4*)&Xs[row * 40 + cq] = xv;
    }
    __syncthreads();
    bf16x8 A[4], Bf[4];
    #pragma unroll
    for (int t = 0; t < 4; ++t) A[t] = *(const bf16x8*)&Ws[(ow_ + t * 16 + m) * 40 + q * 8];
    #pragma unroll
    for (int u = 0; u < 4; ++u) Bf[u] = *(const bf16x8*)&Xs[(lw_ + u * 16 + m) * 40 + q * 8];
    #pragma unroll
    for (int t = 0; t < 4; ++t)
      #pragma unroll
      for (int u = 0; u < 4; ++u)
        acc[t][u] = __builtin_amdgcn_mfma_f32_16x16x32_bf16(A[t], Bf[u], acc[t][u], 0, 0, 0);
    __syncthreads();
  }
  if (act == 3){
    // GLU: reordered rows; pair (even reg r, odd reg r+1); ht row = ro>>1
    #pragma unroll
    for (int t = 0; t < 4; ++t){
      #pragma unroll
      for (int u = 0; u < 4; ++u){
        int l = l0 + lw_ + u * 16 + m;
        #pragma unroll
        for (int r = 0; r < 4; r += 2){
          int ro = o0 + ow_ + t * 16 + q * 4 + r;    // even
          int j = ro >> 1;
          float v1 = acc[t][u][r]   + bias[j];
          float v2 = acc[t][u][r+1] + bias[j + 512];
          out[((size_t)b * 512 + j) * LSEQ + l] = v1 * sigmoid_f(v2);
        }
      }
    }
    return;
  }
  #pragma unroll
  for (int t = 0; t < 4; ++t){
    #pragma unroll
    for (int u = 0; u < 4; ++u){
      int l = l0 + lw_ + u * 16 + m;
      #pragma unroll
      for (int r = 0; r < 4; ++r){
        int o = o0 + ow_ + t * 16 + q * 4 + r;
        if (o >= O) continue;
        size_t oi = ((size_t)b * O + o) * LSEQ + l;
        float v = alpha * acc[t][u][r];
        if (bias) v += bias[o];
        if (res){
          if (sn) v += sn[o] * res[oi] * rinv[b * 2432 + l];
          else v += res[oi];
        }
        if (accf) v += out[oi];
        if (act == 1) v = fmaxf(v, 0.f);
        out[oi] = v * fs;
      }
    }
  }
}

__device__ __forceinline__ bf16x8 s4_mk(u32 a, u32 b, u32 c, u32 d){
  union { u32 u[4]; bf16x8 v; } X; X.u[0]=a; X.u[1]=b; X.u[2]=c; X.u[3]=d; return X.v;
}
#define S4_P16H(a,b) __builtin_amdgcn_perm((a),(b),0x05040100u)
#define S4_P16L(a,b) __builtin_amdgcn_perm((a),(b),0x07060302u)

// ---------- conv3 via MFMA: u = gelu(conv1d(hx+noise, cw(512,256,3), cb, pad1))
// split-bf16 x3 (fp32-class). Wp: u32 hi|lo [512][768] (t-major). Xp: u32 hi|lo [b][2432][256].
__global__ __launch_bounds__(256) void k_conv3m(const u32* __restrict__ Wp,
    const float* __restrict__ bias, const u32* __restrict__ Xp, float* __restrict__ U){
  __shared__ u32 Ws[128 * 36];
  __shared__ u32 Xs[128 * 36];
  int l0 = blockIdx.x * 128, o0 = blockIdx.y * 128, b = blockIdx.z;
  int tid = threadIdx.x;
  int w = tid >> 6, lane = tid & 63;
  int ow_ = (w & 1) * 64, lw_ = (w >> 1) * 64;
  int m = lane & 15, q = (lane >> 4) & 3;
  const u32* Xb = Xp + (size_t)b * 2432 * 256;
  f32x4 acc[4][4] = {};
  for (int s = 0; s < 24; ++s){
    int t = s >> 3, k0 = (s & 7) << 5;
    #pragma unroll
    for (int r = 0; r < 4; ++r){
      int idx = tid + r * 256;                 // 0..1023
      int row = idx >> 3, cq = (idx & 7) * 4;  // 128 rows x 8 chunks of 4 u32
      *(uint4*)&Ws[row * 36 + cq] = *(const uint4*)(Wp + (size_t)(o0 + row) * 768 + t * 256 + k0 + cq);
      int li = l0 + row + t - 1;
      uint4 xv = make_uint4(0u, 0u, 0u, 0u);
      if (li >= 0 && li < 2432) xv = *(const uint4*)(Xb + (size_t)li * 256 + k0 + cq);
      *(uint4*)&Xs[row * 36 + cq] = xv;
    }
    __syncthreads();
    bf16x8 Ah[4], Al[4], Bh[4], Bl[4];
    #pragma unroll
    for (int tt = 0; tt < 4; ++tt){
      const u32* p = &Ws[(ow_ + tt * 16 + m) * 36 + q * 8];
      u32 w0=p[0],w1=p[1],w2=p[2],w3=p[3],w4=p[4],w5=p[5],w6=p[6],w7=p[7];
      Ah[tt] = s4_mk(S4_P16H(w1,w0), S4_P16H(w3,w2), S4_P16H(w5,w4), S4_P16H(w7,w6));
      Al[tt] = s4_mk(S4_P16L(w1,w0), S4_P16L(w3,w2), S4_P16L(w5,w4), S4_P16L(w7,w6));
    }
    #pragma unroll
    for (int uu = 0; uu < 4; ++uu){
      const u32* p = &Xs[(lw_ + uu * 16 + m) * 36 + q * 8];
      u32 w0=p[0],w1=p[1],w2=p[2],w3=p[3],w4=p[4],w5=p[5],w6=p[6],w7=p[7];
      Bh[uu] = s4_mk(S4_P16H(w1,w0), S4_P16H(w3,w2), S4_P16H(w5,w4), S4_P16H(w7,w6));
      Bl[uu] = s4_mk(S4_P16L(w1,w0), S4_P16L(w3,w2), S4_P16L(w5,w4), S4_P16L(w7,w6));
    }
    #pragma unroll
    for (int tt = 0; tt < 4; ++tt)
      #pragma unroll
      for (int uu = 0; uu < 4; ++uu){
        acc[tt][uu] = __builtin_amdgcn_mfma_f32_16x16x32_bf16(Ah[tt], Bh[uu], acc[tt][uu], 0, 0, 0);
        acc[tt][uu] = __builtin_amdgcn_mfma_f32_16x16x32_bf16(Al[tt], Bh[uu], acc[tt][uu], 0, 0, 0);
        acc[tt][uu] = __builtin_amdgcn_mfma_f32_16x16x32_bf16(Ah[tt], Bl[uu], acc[tt][uu], 0, 0, 0);
      }
    __syncthreads();
  }
  #pragma unroll
  for (int tt = 0; tt < 4; ++tt){
    #pragma unroll
    for (int uu = 0; uu < 4; ++uu){
      int l = l0 + lw_ + uu * 16 + m;
      #pragma unroll
      for (int r = 0; r < 4; ++r){
        int o = o0 + ow_ + tt * 16 + q * 4 + r;
        U[((size_t)b * 512 + o) * LSEQ + l] = gelu_f(acc[tt][uu][r] + bias[o]);
      }
    }
  }
}

// ================== S4 via MFMA (Toeplitz GEMM, split-bf16 x3) ==================
#define S4_SU 2464                    // u plane row stride (elements; [2432,2464) zeroed pad)
#define S4_UPLANE (8*S4_SU*2)         // 39424 B per plane
#define S4_ULO  S4_UPLANE             // u_lo plane offset
#define S4_REV  (2*S4_UPLANE)         // 78848
#define S4_TS   (S4_REV + 2856*4)     // 90272
#define S4_LDSZ (S4_TS + 4*576)       // 92576

// fill pipe slot SL with A frag-pair for current Wp (tile-top stream); Wp -= 32
#define S4_FILL(SL) { \
  int Wc = Wp > 0 ? Wp : 0; \
  int ib = rl + Wc; \
  u32 w0=RV[ib], w1=RV[ib+1], w2=RV[ib+2], w3=RV[ib+3], w4=RV[ib+4], w5=RV[ib+5], w6=RV[ib+6], w7=RV[ib+7]; \
  Ph[SL] = s4_mk(S4_P16H(w1,w0), S4_P16H(w3,w2), S4_P16H(w5,w4), S4_P16H(w7,w6)); \
  Pl[SL] = s4_mk(S4_P16L(w1,w0), S4_P16L(w3,w2), S4_P16L(w5,w4), S4_P16L(w7,w6)); \
  Wp -= 32; }

#define S4_MM(ph,d,BH,BL) \
  acc[d] = __builtin_amdgcn_mfma_f32_16x16x32_bf16(Ph[((ph)+5+(d))%12], BH, acc[d], 0, 0, 0); \
  acc[d] = __builtin_amdgcn_mfma_f32_16x16x32_bf16(Pl[((ph)+5+(d))%12], BH, acc[d], 0, 0, 0); \
  acc[d] = __builtin_amdgcn_mfma_f32_16x16x32_bf16(Ph[((ph)+5+(d))%12], BL, acc[d], 0, 0, 0);

// B prefetch: clamp >2400 first (A=0 beyond seq end), then j<0 -> zeroed pad at 2432.
#define S4_PHASE(ph,BC,BN) { \
  S4_FILL(((ph)+4)%12); \
  int bn = j0 - 32; bn = bn > 2400 ? 2400 : bn; bn = bn < 0 ? 2432 : bn; \
  const char* bp = LB + ubo + 2*bn; \
  Bh##BN = *(const bf16x8*)bp; \
  Bl##BN = *(const bf16x8*)(bp + S4_ULO); \
  S4_MM(ph,0,Bh##BC,Bl##BC) S4_MM(ph,1,Bh##BC,Bl##BC) S4_MM(ph,2,Bh##BC,Bl##BC) S4_MM(ph,3,Bh##BC,Bl##BC) \
  S4_MM(ph,4,Bh##BC,Bl##BC) S4_MM(ph,5,Bh##BC,Bl##BC) S4_MM(ph,6,Bh##BC,Bl##BC) S4_MM(ph,7,Bh##BC,Bl##BC) \
  j0 -= 32; }

// One workgroup (4 waves) per h. Each wave sweeps 5 chains of 8 tiles (l spaced 32)
// with a 12-slot rotating A-frag pipe (load once per K-step, shared by all 8 tiles).
// N dim = batch (8 real cols, lanes 8..15 duplicate rows; never written).
// Tail phases (j0<0) read the zeroed B pad -> contribute exactly 0.
// krev staging fused in: RV[e] = packed hi|lo of k[2704-e] (0 outside [0,2432)).
__global__ __launch_bounds__(256, 1) void k_s4m(const float* __restrict__ ksrc,
    const float* __restrict__ Dv, const float* __restrict__ u, float* __restrict__ y){
  extern __shared__ char LB[];
  ushort* UH = (ushort*)LB;
  ushort* UL = (ushort*)(LB + S4_ULO);
  u32* RV = (u32*)(LB + S4_REV);
  int h = blockIdx.x;
  int tid = threadIdx.x;
  // ---- stage u rows (b=0..7) as bf16 hi/lo planes ----
  for (int e = tid; e < 8 * 608; e += 256){
    int b = e / 608, c4 = e % 608;
    float4 v = *(const float4*)(u + ((size_t)b * 512 + h) * 2432 + c4 * 4);
    u32 p0 = packsplit(v.x), p1 = packsplit(v.y), p2 = packsplit(v.z), p3 = packsplit(v.w);
    uint2 hw, lw;
    hw.x = (p0 & 0xffffu) | (p1 << 16);
    hw.y = (p2 & 0xffffu) | (p3 << 16);
    lw.x = (p0 >> 16) | (p1 & 0xffff0000u);
    lw.y = (p2 >> 16) | (p3 & 0xffff0000u);
    *(uint2*)(LB + (size_t)b * (S4_SU*2) + c4 * 8) = hw;
    *(uint2*)(LB + S4_ULO + (size_t)b * (S4_SU*2) + c4 * 8) = lw;
  }
  // ---- zero the 32-element tail pad of every u row (both planes) ----
  if (tid < 256){
    int b = tid >> 5, i = tid & 31;
    UH[b * S4_SU + 2432 + i] = 0;
    UL[b * S4_SU + 2432 + i] = 0;
  }
  // ---- stage reversed-k: pack hi|lo in-kernel (fused k_krev) ----
  {
    const float* kg = ksrc + (size_t)h * 2432;
    for (int e = tid; e < 2856; e += 256){
      u32 v = 0;
      int t = 2704 - e;
      if (t >= 0 && t < 2432) v = packsplit(kg[t]);
      RV[e] = v;
    }
  }
  __syncthreads();

  int lane = tid & 63;
  int wid = __builtin_amdgcn_readfirstlane(tid >> 6);
  int m = lane & 15, qq = lane >> 4;
  int rl = 16 - m + 8 * qq;                       // rev element base (lane const)
  int ubo = (m & 7) * (S4_SU*2) + qq * 16;        // byte offset in u plane
  float dv = Dv[h];
  float* TSp = (float*)(LB + S4_TS + wid * 576);
  static const int GT[2][5] = {{9,6,4,2,0},{8,7,5,3,1}};

  #pragma unroll 1
  for (int c = 0; c < 5; ++c){
    int g = GT[wid >> 1][c];
    int Lb = 256 * g + ((wid & 1) << 4);
    int ltop = Lb + 224;
    int J0 = ((ltop + 15) >> 5) << 5;
    int W0 = 2688 - ltop + J0;
    int NS = (J0 >> 5) + 1;
    int nIt = (NS + 11) / 12;

    f32x4 acc[8];
    bf16x8 Ph[12], Pl[12];
    bf16x8 Bh0, Bl0, Bh1, Bl1;
    {
      f32x4 za = {0.f, 0.f, 0.f, 0.f};
      acc[0]=za; acc[1]=za; acc[2]=za; acc[3]=za; acc[4]=za; acc[5]=za; acc[6]=za; acc[7]=za;
      bf16x8 zz = s4_mk(0u,0u,0u,0u);
      Ph[5]=zz; Ph[6]=zz; Ph[7]=zz; Ph[8]=zz; Ph[9]=zz; Ph[10]=zz; Ph[11]=zz; Ph[4]=zz;
      Pl[5]=zz; Pl[6]=zz; Pl[7]=zz; Pl[8]=zz; Pl[9]=zz; Pl[10]=zz; Pl[11]=zz; Pl[4]=zz;
    }
    int Wp = W0;
    S4_FILL(0) S4_FILL(1) S4_FILL(2) S4_FILL(3)
    int j0 = J0;
    {
      int bj0 = j0 > 2400 ? 2400 : j0;
      const char* bp0 = LB + ubo + 2 * bj0;
      Bh0 = *(const bf16x8*)bp0;
      Bl0 = *(const bf16x8*)(bp0 + S4_ULO);
    }
    #pragma unroll 1
    for (int it = 0; it < nIt; ++it){
      S4_PHASE(0,0,1) S4_PHASE(1,1,0) S4_PHASE(2,0,1) S4_PHASE(3,1,0)
      S4_PHASE(4,0,1) S4_PHASE(5,1,0) S4_PHASE(6,0,1) S4_PHASE(7,1,0)
      S4_PHASE(8,0,1) S4_PHASE(9,1,0) S4_PHASE(10,0,1) S4_PHASE(11,1,0)
    }
    // ---- epilogue: per-wave LDS transpose + D skip, coalesced y write ----
    #pragma unroll
    for (int d = 0; d < 8; ++d){
      int ld = Lb + 32 * d;
      if (ld < 2432){
        if (m < 8){
          TSp[(qq*4+0)*9 + m] = acc[d][0];
          TSp[(qq*4+1)*9 + m] = acc[d][1];
          TSp[(qq*4+2)*9 + m] = acc[d][2];
          TSp[(qq*4+3)*9 + m] = acc[d][3];
        }
        __builtin_amdgcn_wave_barrier();
        #pragma unroll
        for (int p = 0; p < 2; ++p){
          int li = lane & 15, bb = (lane >> 4) + 4 * p;
          float v = TSp[li*9 + bb];
          int l = ld + li;
          float uv = bfu2f(UH[bb * S4_SU + l]) + bfu2f(UL[bb * S4_SU + l]);
          y[((size_t)bb * 512 + h) * 2432 + l] = v + dv * uv;
        }
        __builtin_amdgcn_wave_barrier();
      }
    }
  }
}

// ---------- final LayerNorm over last dim (200) with transpose
__global__ __launch_bounds__(256) void k_ln(const float* __restrict__ o2,
    const float* __restrict__ lw, const float* __restrict__ lb2, float* __restrict__ out){
  __shared__ float s1[256], s2[256];
  int row = blockIdx.x;
  int b = row / 2432, l = row % 2432;
  int t = threadIdx.x;
  float v = 0.f;
  if (t < 200) v = o2[((size_t)b * 200 + t) * LSEQ + l];
  s1[t] = v; s2[t] = v * v;
  __syncthreads();
  for (int off = 128; off > 0; off >>= 1){
    if (t < off){ s1[t] += s1[t + off]; s2[t] += s2[t + off]; }
    __syncthreads();
  }
  float m = s1[0] * 0.005f;
  float var = s2[0] * 0.005f - m * m;
  float istd = rsqrtf(var + 1e-5f);
  if (t < 200) out[(size_t)row * 200 + t] = (v - m) * istd * lw[t] + lb2[t];
}

extern "C" void kernel_launch(void* const* d_in, const int* in_sizes, int n_in,
                              void* d_out, int out_size, void* d_ws, size_t ws_size,
                              hipStream_t stream){
  const float* x     = (const float*)d_in[0];
  const float* pe_w  = (const float*)d_in[1];
  const float* pe_b  = (const float*)d_in[2];
  const float* pi0_w = (const float*)d_in[3];
  const float* pi0_b = (const float*)d_in[4];
  const float* gn0_w = (const float*)d_in[5];
  const float* gn0_b = (const float*)d_in[6];
  const float* pi1_w = (const float*)d_in[7];
  const float* pi1_b = (const float*)d_in[8];
  const float* gn1_w = (const float*)d_in[9];
  const float* gn1_b = (const float*)d_in[10];
  const float* pi2_w = (const float*)d_in[11];
  const float* pi2_b = (const float*)d_in[12];
  const float* gn2_w = (const float*)d_in[13];
  const float* gn2_b = (const float*)d_in[14];
  const float* spec_w= (const float*)d_in[15];
  const float* spec_b= (const float*)d_in[16];
  const float* ic_w  = (const float*)d_in[17];
  const float* ic_b  = (const float*)d_in[18];
  const float* blk_sn= (const float*)d_in[19];
  const float* blk_cw= (const float*)d_in[20];
  const float* blk_cb= (const float*)d_in[21];
  const float* blk_k = (const float*)d_in[22];
  const float* blk_D = (const float*)d_in[23];
  const float* blk_ow= (const float*)d_in[24];
  const float* blk_ob= (const float*)d_in[25];
  const float* blk_Wv= (const float*)d_in[26];
  const float* blk_bv= (const float*)d_in[27];
  const float* blk_Wo= (const float*)d_in[28];
  const float* blk_bo= (const float*)d_in[29];
  const float* blk_rw= (const float*)d_in[30];
  const float* blk_rb= (const float*)d_in[31];
  const float* blk_sw= (const float*)d_in[32];
  const float* blk_sb= (const float*)d_in[33];
  const float* fc_w  = (const float*)d_in[34];
  const float* fc_b  = (const float*)d_in[35];
  const float* zc_w  = (const float*)d_in[36];
  const float* zc_b  = (const float*)d_in[37];
  const float* ln_w  = (const float*)d_in[38];
  const float* ln_b  = (const float*)d_in[39];

  // allow >64KB dynamic LDS for k_s4m (host-side, graph-capture safe)
  static int s4m_attr = 0;
  if (!s4m_attr){
    hipFuncSetAttribute(reinterpret_cast<const void*>(k_s4m),
                        hipFuncAttributeMaxDynamicSharedMemorySize, S4_LDSZ);
    s4m_attr = 1;
  }

  float* Wsp = (float*)d_ws;
  const size_t NLL = (size_t)8 * 256 * 2432;    // 4,980,736 floats
  float* noise = Wsp;                 // [0,1)
  float* hxb   = Wsp + NLL;           // [1,2)
  float* skb   = Wsp + 2 * NLL;       // [2,3)
  float* ub    = Wsp + 3 * NLL;       // [3,5)  u / v / a / fc-out
  float* ysb   = Wsp + 5 * NLL;       // [5,7)  s4-out per s / ht / zc-out
  float* htb   = ysb;
  unsigned short* actT = (unsigned short*)(Wsp + 7 * NLL);   // [7,11) bf16 [b][l][2048]
  unsigned short* wB = (unsigned short*)(Wsp + 11 * NLL);
  unsigned short* owB = wB;                    // 6*1024*2048 = 12,582,912
  unsigned short* WvB = wB + 12582912;         // 1,572,864
  unsigned short* WoB = wB + 14155776;         // 1,572,864
  unsigned short* rwB = wB + 15728640;         // 393,216
  unsigned short* swB = wB + 16121856;         // 393,216
  unsigned short* icB = wB + 16515072;         // 57,344
  unsigned short* fcB = wB + 16572416;         // 65,536
  unsigned short* zcB = wB + 16637952;         // 51,200 -> end 16,689,152 ushorts
  float* rinv   = Wsp + 11 * NLL + 8344576;    // 19,456 floats
  float* gnstats= rinv + 19456;                // 80 floats
  u32* WpB = (u32*)(Wsp + 63152208);           // conv3 packed W: 393,216 dwords (old krev region)
  u32* XpT = (u32*)(Wsp + 7 * NLL);            // conv3 packed X: 4,980,736 dwords (actT region, dead then)

  // front-end aliases (regions dead at that point)
  float* p0 = ub;
  float* p1 = ysb;
  float* p2 = ub;
  float* pe = Wsp + 7 * NLL;          // actT region (floats), dead before first castT use
  float* spec = Wsp + 8 * NLL;
  float* peT = skb;                   // skb garbage OK (first sw gemm accf=0)
  float* hb = hxb;                    // overwritten later by memcpy noise->hxb

  const float SQ05 = 0.70710678118654752440f;
  const float SQ16 = 0.40824829046386301637f;

  // ---- weight casts (bf16) ----
  k_wcast_glu<<<49152,256,0,stream>>>(blk_ow, owB);
  k_wcast<<<(3072*512+255)/256,256,0,stream>>>(blk_Wv, WvB, 3072, 512, 512);
  k_wcast<<<(3072*512+255)/256,256,0,stream>>>(blk_Wo, WoB, 3072, 512, 512);
  k_wcast<<<(1536*256+255)/256,256,0,stream>>>(blk_rw, rwB, 1536, 256, 256);
  k_wcast<<<(1536*256+255)/256,256,0,stream>>>(blk_sw, swB, 1536, 256, 256);
  k_wcast<<<(256*224+255)/256,256,0,stream>>>(ic_w, icB, 256, 200, 224);
  k_wcast<<<(256*256+255)/256,256,0,stream>>>(fc_w, fcB, 256, 256, 256);
  k_wcast<<<(200*256+255)/256,256,0,stream>>>(zc_w, zcB, 200, 256, 256);

  // ---- PatchEmbedding ----
  k_pi0<<<dim3(76,25,8), 256, 0, stream>>>(x, pi0_w, pi0_b, p0);
  k_gn_reduce<<<40,256,0,stream>>>(p0, gnstats);
  k_gn_apply<<<15200,256,0,stream>>>(p0, gnstats, gn0_w, gn0_b);
  k_pconv3<<<dim3(76,25,8),256,0,stream>>>(p0, pi1_w, pi1_b, p1);
  k_gn_reduce<<<40,256,0,stream>>>(p1, gnstats);
  k_gn_apply<<<15200,256,0,stream>>>(p1, gnstats, gn1_w, gn1_b);
  k_pconv3<<<dim3(76,25,8),256,0,stream>>>(p1, pi2_w, pi2_b, p2);
  k_gn_reduce<<<40,256,0,stream>>>(p2, gnstats);
  k_gn_apply<<<15200,256,0,stream>>>(p2, gnstats, gn2_w, gn2_b);
  k_pe_build<<<15200,256,0,stream>>>(p2, pe);
  k_spec<<<19456,256,0,stream>>>(x, spec);
  k_spec_mm<<<19456,256,0,stream>>>(spec, spec_w, spec_b, pe);
  k_trp<<<dim3(76,7,8),256,0,stream>>>(pe, peT);
  k_hbuild2<<<dim3(19,200,8),128,0,stream>>>(peT, pe_w, pe_b, hb);
  k_castT<<<dim3(76,7,8),256,0,stream>>>(hb, actT, 200, 224, 0);
  k_bgemm<<<dim3(19,2,8),256,0,stream>>>(icB, actT, ic_b, nullptr, nullptr, nullptr,
                                         noise, 256, 224, 1.f, 1.f, 1, 0);
  hipMemcpyAsync(hxb, noise, NLL * sizeof(float), hipMemcpyDeviceToDevice, stream);

  // ---- residual blocks ----
  for (int i = 0; i < 6; ++i){
    const float* sn = blk_sn + i * 256;
    const float* cw = blk_cw + (size_t)i * 512 * 768;
    const float* cb = blk_cb + i * 512;
    const float* ob = blk_ob + i * 1024;
    const float* bv = blk_bv + i * 512;
    const float* bo = blk_bo + i * 512;
    const float* rb = blk_rb + i * 256;
    const float* sb = blk_sb + i * 256;

    k_rmsr<<<76,256,0,stream>>>(hxb, rinv);
    // conv3 via MFMA: pack X (hx+noise, transposed) and W, then GEMM
    k_packT<<<dim3(76,8,8),256,0,stream>>>(hxb, noise, XpT);
    k_wpack3<<<1536,256,0,stream>>>(cw, WpB);
    k_conv3m<<<dim3(19,4,8),256,0,stream>>>(WpB, cb, XpT, ub);
    for (int s = 0; s < 4; ++s){
      const float* kw = blk_k + ((size_t)i * 4 + s) * 512 * 2432;
      const float* Dvp = blk_D + ((size_t)i * 4 + s) * 512;
      k_s4m<<<dim3(512),256,S4_LDSZ,stream>>>(kw, Dvp, ub, ysb);
      k_castT<<<dim3(76,16,8),256,0,stream>>>(ysb, actT, 512, 2048, s * 512);
    }
    // fused ow-GEMM + GLU -> ht (512 ch)
    k_bgemm<<<dim3(19,8,8),256,0,stream>>>(owB + (size_t)i*1024*2048, actT, ob,
                                           nullptr, nullptr, nullptr, htb,
                                           1024, 2048, 1.f, 1.f, 3, 0);
    k_castT<<<dim3(76,16,8),256,0,stream>>>(htb, actT, 512, 512, 0);
    k_bgemm<<<dim3(19,4,8),256,0,stream>>>(WvB + (size_t)i*512*512, actT, bv,
                                           nullptr, nullptr, nullptr, ub,
                                           512, 512, 1.f, 1.f, 0, 0);
    k_castT<<<dim3(76,16,8),256,0,stream>>>(ub, actT, 512, 512, 0);
    k_bgemm<<<dim3(19,4,8),256,0,stream>>>(WoB + (size_t)i*512*512, actT, bo,
                                           nullptr, nullptr, nullptr, ub,
                                           512, 512, 1.f, 1.f, 0, 0);
    k_gateT<<<dim3(76,8,8),256,0,stream>>>(htb, ub, actT);
    // rw-GEMM with fused RMS residual: hx = (sn*hx*rinv + rw@out + rb)*sqrt(0.5)
    k_bgemm<<<dim3(19,2,8),256,0,stream>>>(rwB + (size_t)i*256*256, actT, rb,
                                           hxb, sn, rinv, hxb,
                                           256, 256, 1.f, SQ05, 0, 0);
    k_bgemm<<<dim3(19,2,8),256,0,stream>>>(swB + (size_t)i*256*256, actT, sb,
                                           nullptr, nullptr, nullptr, skb,
                                           256, 256, 1.f, 1.f, 0, i==0?0:1);
  }

  // ---- tail ----
  k_castT<<<dim3(76,8,8),256,0,stream>>>(skb, actT, 256, 256, 0);
  k_bgemm<<<dim3(19,2,8),256,0,stream>>>(fcB, actT, fc_b, nullptr, nullptr, nullptr,
                                         ub, 256, 256, SQ16, 1.f, 1, 0);
  k_castT<<<dim3(76,8,8),256,0,stream>>>(ub, actT, 256, 256, 0);
  k_bgemm<<<dim3(19,2,8),256,0,stream>>>(zcB, actT, zc_b, nullptr, nullptr, nullptr,
                                         ysb, 200, 256, 1.f, 1.f, 0, 0);
  k_ln<<<19456,256,0,stream>>>(ysb, ln_w, ln_b, (float*)d_out);
}

// Round 5
// 8430.277 us; speedup vs baseline: 2.3144x; 1.1162x over previous
//
#include <hip/hip_runtime.h>
#include <hip/hip_bf16.h>
#include <math.h>

#define LSEQ 2432

typedef short bf16x8 __attribute__((ext_vector_type(8)));
typedef float f32x4 __attribute__((ext_vector_type(4)));
typedef unsigned int u32;

__device__ __forceinline__ float gelu_f(float x){
  return 0.5f * x * (1.0f + erff(x * 0.70710678118654752440f));
}
__device__ __forceinline__ float sigmoid_f(float x){
  return 1.0f / (1.0f + __expf(-x));
}
__device__ __forceinline__ unsigned short f2bf(float f){
  __hip_bfloat16 h = __float2bfloat16(f);   // RNE
  return *reinterpret_cast<unsigned short*>(&h);
}
__device__ __forceinline__ float bfu2f(unsigned short s){
  union { u32 u; float f; } X; X.u = ((u32)s) << 16; return X.f;
}
// split f32 -> (hi bf16 in low16, lo bf16 in high16)
__device__ __forceinline__ u32 packsplit(float v){
  unsigned short hi = f2bf(v);
  float lo = v - bfu2f(hi);
  unsigned short ls = f2bf(lo);
  return (u32)hi | ((u32)ls << 16);
}

// ---------- pi0 (LDS-staged): block = 32 rows x 1 batch; thread = (row,wv); loop o
__global__ __launch_bounds__(256) void k_pi0b(const float* __restrict__ x,
    const float* __restrict__ w, const float* __restrict__ bias,
    float* __restrict__ out){
  __shared__ float xs[32][200];
  __shared__ float ws[25][49];
  __shared__ float bs[25];
  int r0 = blockIdx.x * 32, b = blockIdx.y;
  int tid = threadIdx.x;
  const float* xb = x + ((size_t)b * 2432 + r0) * 200;
  for (int e = tid; e < 1600; e += 256){
    int row = e / 50, c4 = e % 50;
    *(float4*)&xs[row][c4 * 4] = *(const float4*)(xb + row * 200 + c4 * 4);
  }
  for (int e = tid; e < 1225; e += 256) ws[e / 49][e % 49] = w[e];
  if (tid < 25) bs[tid] = bias[tid];
  __syncthreads();
  int row = tid >> 3, wv = tid & 7;
  int start = wv * 25 - 24;
  float tap[49];
  #pragma unroll
  for (int t = 0; t < 49; ++t){
    int ix = start + t;
    tap[t] = (ix >= 0 && ix < 200) ? xs[row][ix] : 0.f;
  }
  for (int o = 0; o < 25; ++o){
    float acc = bs[o];
    #pragma unroll
    for (int t = 0; t < 49; ++t) acc += tap[t] * ws[o][t];
    out[(((size_t)b * 25 + o) * 2432 + (r0 + row)) * 8 + wv] = acc;
  }
}

// ---------- group norm (groups=5 over 25 ch)
__global__ __launch_bounds__(256) void k_gn_reduce(const float* __restrict__ p, float* __restrict__ stats){
  int b = blockIdx.x / 5, g = blockIdx.x % 5;
  const float* base = p + ((size_t)b * 25 + g * 5) * 19456;
  float s = 0.f, s2 = 0.f;
  for (int i = threadIdx.x; i < 97280; i += 256){ float v = base[i]; s += v; s2 += v * v; }
  __shared__ float sh[256], sh2[256];
  int t = threadIdx.x;
  sh[t] = s; sh2[t] = s2; __syncthreads();
  for (int off = 128; off > 0; off >>= 1){
    if (t < off){ sh[t] += sh[t+off]; sh2[t] += sh2[t+off]; }
    __syncthreads();
  }
  if (t == 0){
    float m = sh[0] / 97280.f;
    float var = sh2[0] / 97280.f - m * m;
    stats[blockIdx.x * 2] = m;
    stats[blockIdx.x * 2 + 1] = rsqrtf(var + 1e-5f);
  }
}

__global__ __launch_bounds__(256) void k_gn_apply(float* __restrict__ p, const float* __restrict__ stats,
    const float* __restrict__ gw, const float* __restrict__ gb){
  size_t i = (size_t)blockIdx.x * 256 + threadIdx.x;
  int c = (int)((i / 19456) % 25);
  int b = (int)(i / 486400);
  int g = c / 5;
  float m = stats[(b*5+g)*2], istd = stats[(b*5+g)*2+1];
  float v = (p[i] - m) * istd * gw[c] + gb[c];
  p[i] = gelu_f(v);
}

// ---------- pconv3 (LDS-staged): block = 32 rows x 1 batch; thread = (row,wv); loop o
__global__ __launch_bounds__(256) void k_pconv3b(const float* __restrict__ pin,
    const float* __restrict__ w, const float* __restrict__ bias, float* __restrict__ pout){
  __shared__ float T[25][256];    // [i][row*8+wv]
  __shared__ float ws[25][75];
  __shared__ float bs[25];
  int r0 = blockIdx.x * 32, b = blockIdx.y;
  int tid = threadIdx.x;
  const float* pb = pin + (size_t)b * 25 * 19456 + r0 * 8;
  for (int e = tid; e < 25 * 64; e += 256){
    int i = e / 64, c4 = e % 64;
    *(float4*)&T[i][c4 * 4] = *(const float4*)(pb + (size_t)i * 19456 + c4 * 4);
  }
  for (int e = tid; e < 1875; e += 256) ws[e / 75][e % 75] = w[e];
  if (tid < 25) bs[tid] = bias[tid];
  __syncthreads();
  int wv = tid & 7;
  float xm[25], x0[25], xp[25];
  #pragma unroll
  for (int i = 0; i < 25; ++i){
    x0[i] = T[i][tid];
    xm[i] = (wv > 0) ? T[i][tid - 1] : 0.f;
    xp[i] = (wv < 7) ? T[i][tid + 1] : 0.f;
  }
  for (int o = 0; o < 25; ++o){
    float acc = bs[o];
    #pragma unroll
    for (int i = 0; i < 25; ++i)
      acc += xm[i] * ws[o][i*3] + x0[i] * ws[o][i*3+1] + xp[i] * ws[o][i*3+2];
    pout[(((size_t)b * 25 + o) * 2432 + r0) * 8 + tid] = acc;
  }
}

// ---------- pe[b,l,p] = p2[b, p>>3, l, p&7]
__global__ __launch_bounds__(256) void k_pe_build(const float* __restrict__ p2, float* __restrict__ pe){
  size_t i = (size_t)blockIdx.x * 256 + threadIdx.x;
  int p = (int)(i % 200);
  size_t rem = i / 200;
  int l = (int)(rem % 2432);
  int b = (int)(rem / 2432);
  pe[i] = p2[(((size_t)b*25 + (p>>3)) * 2432 + l) * 8 + (p & 7)];
}

// ---------- spec = |DFT_200(x)| / 200  (101 bins)
__global__ __launch_bounds__(256) void k_spec(const float* __restrict__ x, float* __restrict__ spec){
  __shared__ float xr[200], ct[200], st[200];
  int row = blockIdx.x;
  int t = threadIdx.x;
  if (t < 200){
    xr[t] = x[(size_t)row * 200 + t];
    float ang = -0.031415926535897932385f * t;
    ct[t] = cosf(ang); st[t] = sinf(ang);
  }
  __syncthreads();
  if (t < 101){
    float re = 0.f, im = 0.f;
    int ph = 0;
    for (int k = 0; k < 200; ++k){
      re += xr[k] * ct[ph];
      im += xr[k] * st[ph];
      ph += t; if (ph >= 200) ph -= 200;
    }
    spec[(size_t)row * 101 + t] = sqrtf(re*re + im*im) * 0.005f;
  }
}

// ---------- pe += spec @ spec_w^T + spec_b
__global__ __launch_bounds__(256) void k_spec_mm(const float* __restrict__ spec,
    const float* __restrict__ sw, const float* __restrict__ sb, float* __restrict__ pe){
  __shared__ float sr[101];
  int row = blockIdx.x;
  int t = threadIdx.x;
  if (t < 101) sr[t] = spec[(size_t)row * 101 + t];
  __syncthreads();
  if (t < 200){
    const float* wr = sw + t * 101;
    float acc = sb[t];
    for (int f = 0; f < 101; ++f) acc += sr[f] * wr[f];
    pe[(size_t)row * 200 + t] += acc;
  }
}

// ---------- pe (b,L,200) -> peT (b,200,L), 32x32 LDS tiles
__global__ __launch_bounds__(256) void k_trp(const float* __restrict__ pe, float* __restrict__ peT){
  __shared__ float ts[32][33];
  int l0 = blockIdx.x * 32, c0 = blockIdx.y * 32, b = blockIdx.z;
  int t = threadIdx.x;
  int i = t >> 5, j = t & 31;
  #pragma unroll
  for (int pass = 0; pass < 4; ++pass){
    int ii = i + pass * 8;
    int c = c0 + j;
    ts[ii][j] = (c < 200) ? pe[((size_t)b * 2432 + l0 + ii) * 200 + c] : 0.f;
  }
  __syncthreads();
  #pragma unroll
  for (int pass = 0; pass < 4; ++pass){
    int ii = i + pass * 8;
    int c = c0 + ii;
    if (c < 200) peT[((size_t)b * 200 + c) * 2432 + l0 + j] = ts[j][ii];
  }
}

// ---------- hbuild: h[b,p,c*128+j] = peT[b,p,c*128+j] + depthwise19x7 conv
__global__ __launch_bounds__(128) void k_hbuild2(const float* __restrict__ peT,
    const float* __restrict__ pw, const float* __restrict__ pb, float* __restrict__ h){
  __shared__ float T[19][136];
  __shared__ float wsh[133];
  int c = blockIdx.x, p = blockIdx.y, b = blockIdx.z;
  int tid = threadIdx.x;
  const float* pr = peT + ((size_t)b * 200 + p) * 2432;
  for (int e = tid; e < 19 * 136; e += 128){
    int a = e / 136, m = e % 136;
    int hh = c - 9 + a, ww = m - 3;
    float v = 0.f;
    if (hh >= 0 && hh < 19 && ww >= 0 && ww < 128) v = pr[hh * 128 + ww];
    T[a][m] = v;
  }
  for (int e = tid; e < 133; e += 128) wsh[e] = pw[p * 133 + e];
  __syncthreads();
  int j = tid;
  float conv = pb[p];
  #pragma unroll
  for (int a = 0; a < 19; ++a){
    #pragma unroll
    for (int tt = 0; tt < 7; ++tt) conv += T[a][j + tt] * wsh[a * 7 + tt];
  }
  float orig = T[9][j + 3];
  h[((size_t)b * 200 + p) * 2432 + c * 128 + j] = orig + conv;
}

// ---------- weight cast f32 [O][Kin] -> bf16 [O][Kpad] (zero pad)
__global__ __launch_bounds__(256) void k_wcast(const float* __restrict__ src,
    unsigned short* __restrict__ dst, int O, int Kin, int Kpad){
  size_t i = (size_t)blockIdx.x * 256 + threadIdx.x;
  if (i >= (size_t)O * Kpad) return;
  int k = (int)(i % Kpad);
  int o = (int)(i / Kpad);
  dst[i] = (k < Kin) ? f2bf(src[(size_t)o * Kin + k]) : 0;
}

// ---------- ow cast with GLU row interleave: dst row ro <- src row (ro>>1)+(ro&1)*512
__global__ __launch_bounds__(256) void k_wcast_glu(const float* __restrict__ src,
    unsigned short* __restrict__ dst){
  size_t i = (size_t)blockIdx.x * 256 + threadIdx.x;
  if (i >= (size_t)6 * 1024 * 2048) return;
  int k = (int)(i % 2048);
  size_t rem = i / 2048;
  int ro = (int)(rem % 1024);
  int blk = (int)(rem / 1024);
  int j = (ro >> 1) + (ro & 1) * 512;
  dst[i] = f2bf(src[((size_t)blk * 1024 + j) * 2048 + k]);
}

// ---------- cast+transpose f32 [b][C][L] -> bf16 [b][L][Kpad] cols [cbase, cbase+C)
__global__ __launch_bounds__(256) void k_castT(const float* __restrict__ in,
    unsigned short* __restrict__ out, int C, int Kpad, int cbase){
  __shared__ float ts[32][33];
  int l0 = blockIdx.x * 32, c0 = blockIdx.y * 32, b = blockIdx.z;
  int t = threadIdx.x;
  int i = t >> 5, j = t & 31;
  #pragma unroll
  for (int pass = 0; pass < 4; ++pass){
    int ci = c0 + i + pass * 8;
    ts[i + pass * 8][j] = (ci < C) ? in[((size_t)b * C + ci) * LSEQ + l0 + j] : 0.f;
  }
  __syncthreads();
  #pragma unroll
  for (int pass = 0; pass < 4; ++pass){
    int li = l0 + i + pass * 8;
    out[((size_t)b * LSEQ + li) * Kpad + cbase + c0 + j] = f2bf(ts[j][i + pass * 8]);
  }
}

// ---------- pack+transpose (hx+noise) f32 [b][256][L] -> u32 hi|lo [b][L][256]
__global__ __launch_bounds__(256) void k_packT(const float* __restrict__ A,
    const float* __restrict__ N, u32* __restrict__ out){
  __shared__ float ts[32][33];
  int l0 = blockIdx.x * 32, c0 = blockIdx.y * 32, b = blockIdx.z;
  int t = threadIdx.x;
  int i = t >> 5, j = t & 31;
  #pragma unroll
  for (int pass = 0; pass < 4; ++pass){
    int ci = c0 + i + pass * 8;
    size_t ii = ((size_t)b * 256 + ci) * LSEQ + l0 + j;
    ts[i + pass * 8][j] = A[ii] + N[ii];
  }
  __syncthreads();
  #pragma unroll
  for (int pass = 0; pass < 4; ++pass){
    int li = l0 + i + pass * 8;
    out[((size_t)b * LSEQ + li) * 256 + c0 + j] = packsplit(ts[j][i + pass * 8]);
  }
}

// ---------- pack conv3 weights: Wp[o][t*256+c] = packsplit(cw[o][c][t])
__global__ __launch_bounds__(256) void k_wpack3(const float* __restrict__ cw, u32* __restrict__ Wp){
  int i = blockIdx.x * 256 + threadIdx.x;     // 512*768
  int o = i / 768, rem = i % 768;
  int t = rem / 256, c = rem % 256;
  Wp[i] = packsplit(cw[((size_t)o * 256 + c) * 3 + t]);
}

// ---------- gate fused with cast+transpose: actT[b][l][c] = bf16(tanh(g1)*sigmoid(g2))
__global__ __launch_bounds__(256) void k_gateT(const float* __restrict__ ht,
    const float* __restrict__ a, unsigned short* __restrict__ out){
  __shared__ float ts[32][33];
  int l0 = blockIdx.x * 32, c0 = blockIdx.y * 32, b = blockIdx.z;
  int t = threadIdx.x;
  int i = t >> 5, j = t & 31;
  #pragma unroll
  for (int pass = 0; pass < 4; ++pass){
    int ci = c0 + i + pass * 8;
    size_t i1 = ((size_t)b * 512 + ci) * LSEQ + l0 + j;
    size_t i2 = ((size_t)b * 512 + ci + 256) * LSEQ + l0 + j;
    float g1 = ht[i1] + a[i1];
    float g2 = ht[i2] + a[i2];
    ts[i + pass * 8][j] = tanhf(g1) * sigmoid_f(g2);
  }
  __syncthreads();
  #pragma unroll
  for (int pass = 0; pass < 4; ++pass){
    int li = l0 + i + pass * 8;
    out[((size_t)b * LSEQ + li) * 256 + c0 + j] = f2bf(ts[j][i + pass * 8]);
  }
}

// ---------- rms inverse scale per (b,l)
__global__ __launch_bounds__(256) void k_rmsr(const float* __restrict__ hx, float* __restrict__ rinv){
  int idx = blockIdx.x * 256 + threadIdx.x;   // 19456
  int b = idx / 2432, l = idx % 2432;
  const float* p = hx + (size_t)b * 256 * LSEQ + l;
  float s = 0.f;
  #pragma unroll 8
  for (int c = 0; c < 256; ++c){ float v = p[(size_t)c * LSEQ]; s += v * v; }
  rinv[idx] = 1.0f / (sqrtf(s * (1.0f/256.0f)) + 1e-8f);
}

// ---------- bf16 MFMA GEMM.
// act: 0 none, 1 relu, 3 GLU(pair rows -> out has O/2=512 rows)
// res2 mode (sn!=nullptr): v += sn[o]*res[oi]*rinv[b*2432+l]
__global__ __launch_bounds__(256) void k_bgemm(const unsigned short* __restrict__ Wb,
    const unsigned short* __restrict__ Xb, const float* __restrict__ bias,
    const float* __restrict__ res, const float* __restrict__ sn,
    const float* __restrict__ rinv, float* __restrict__ out,
    int O, int Kpad, float alpha, float fs, int act, int accf){
  __shared__ unsigned short Ws[128 * 40];
  __shared__ unsigned short Xs[128 * 40];
  int l0 = blockIdx.x * 128, o0 = blockIdx.y * 128, b = blockIdx.z;
  int tid = threadIdx.x;
  int w = tid >> 6, lane = tid & 63;
  int ow_ = (w & 1) * 64, lw_ = (w >> 1) * 64;
  int m = lane & 15, q = (lane >> 4) & 3;
  const unsigned short* Xbb = Xb + (size_t)b * 2432 * Kpad;
  f32x4 acc[4][4] = {};
  for (int k0 = 0; k0 < Kpad; k0 += 32){
    #pragma unroll
    for (int r = 0; r < 2; ++r){
      int idx = tid + r * 256;
      int row = idx >> 2, cq = (idx & 3) * 8;
      uint4 v = make_uint4(0u, 0u, 0u, 0u);
      int o = o0 + row;
      if (o < O) v = *(const uint4*)(Wb + (size_t)o * Kpad + k0 + cq);
      *(uint4*)&Ws[row * 40 + cq] = v;
      uint4 xv = *(const uint4*)(Xbb + (size_t)(l0 + row) * Kpad + k0 + cq);
      *(uint4*)&Xs[row * 40 + cq] = xv;
    }
    __syncthreads();
    bf16x8 A[4], Bf[4];
    #pragma unroll
    for (int t = 0; t < 4; ++t) A[t] = *(const bf16x8*)&Ws[(ow_ + t * 16 + m) * 40 + q * 8];
    #pragma unroll
    for (int u = 0; u < 4; ++u) Bf[u] = *(const bf16x8*)&Xs[(lw_ + u * 16 + m) * 40 + q * 8];
    #pragma unroll
    for (int t = 0; t < 4; ++t)
      #pragma unroll
      for (int u = 0; u < 4; ++u)
        acc[t][u] = __builtin_amdgcn_mfma_f32_16x16x32_bf16(A[t], Bf[u], acc[t][u], 0, 0, 0);
    __syncthreads();
  }
  if (act == 3){
    // GLU: reordered rows; pair (even reg r, odd reg r+1); ht row = ro>>1
    #pragma unroll
    for (int t = 0; t < 4; ++t){
      #pragma unroll
      for (int u = 0; u < 4; ++u){
        int l = l0 + lw_ + u * 16 + m;
        #pragma unroll
        for (int r = 0; r < 4; r += 2){
          int ro = o0 + ow_ + t * 16 + q * 4 + r;    // even
          int j = ro >> 1;
          float v1 = acc[t][u][r]   + bias[j];
          float v2 = acc[t][u][r+1] + bias[j + 512];
          out[((size_t)b * 512 + j) * LSEQ + l] = v1 * sigmoid_f(v2);
        }
      }
    }
    return;
  }
  #pragma unroll
  for (int t = 0; t < 4; ++t){
    #pragma unroll
    for (int u = 0; u < 4; ++u){
      int l = l0 + lw_ + u * 16 + m;
      #pragma unroll
      for (int r = 0; r < 4; ++r){
        int o = o0 + ow_ + t * 16 + q * 4 + r;
        if (o >= O) continue;
        size_t oi = ((size_t)b * O + o) * LSEQ + l;
        float v = alpha * acc[t][u][r];
        if (bias) v += bias[o];
        if (res){
          if (sn) v += sn[o] * res[oi] * rinv[b * 2432 + l];
          else v += res[oi];
        }
        if (accf) v += out[oi];
        if (act == 1) v = fmaxf(v, 0.f);
        out[oi] = v * fs;
      }
    }
  }
}

__device__ __forceinline__ bf16x8 s4_mk(u32 a, u32 b, u32 c, u32 d){
  union { u32 u[4]; bf16x8 v; } X; X.u[0]=a; X.u[1]=b; X.u[2]=c; X.u[3]=d; return X.v;
}
#define S4_P16H(a,b) __builtin_amdgcn_perm((a),(b),0x05040100u)
#define S4_P16L(a,b) __builtin_amdgcn_perm((a),(b),0x07060302u)

// ---------- conv3 via MFMA: u = gelu(conv1d(hx+noise, cw(512,256,3), cb, pad1))
// split-bf16 x3 (fp32-class). Wp: u32 hi|lo [512][768] (t-major). Xp: u32 hi|lo [b][2432][256].
__global__ __launch_bounds__(256) void k_conv3m(const u32* __restrict__ Wp,
    const float* __restrict__ bias, const u32* __restrict__ Xp, float* __restrict__ U){
  __shared__ u32 Ws[128 * 36];
  __shared__ u32 Xs[128 * 36];
  int l0 = blockIdx.x * 128, o0 = blockIdx.y * 128, b = blockIdx.z;
  int tid = threadIdx.x;
  int w = tid >> 6, lane = tid & 63;
  int ow_ = (w & 1) * 64, lw_ = (w >> 1) * 64;
  int m = lane & 15, q = (lane >> 4) & 3;
  const u32* Xb = Xp + (size_t)b * 2432 * 256;
  f32x4 acc[4][4] = {};
  for (int s = 0; s < 24; ++s){
    int t = s >> 3, k0 = (s & 7) << 5;
    #pragma unroll
    for (int r = 0; r < 4; ++r){
      int idx = tid + r * 256;                 // 0..1023
      int row = idx >> 3, cq = (idx & 7) * 4;  // 128 rows x 8 chunks of 4 u32
      *(uint4*)&Ws[row * 36 + cq] = *(const uint4*)(Wp + (size_t)(o0 + row) * 768 + t * 256 + k0 + cq);
      int li = l0 + row + t - 1;
      uint4 xv = make_uint4(0u, 0u, 0u, 0u);
      if (li >= 0 && li < 2432) xv = *(const uint4*)(Xb + (size_t)li * 256 + k0 + cq);
      *(uint4*)&Xs[row * 36 + cq] = xv;
    }
    __syncthreads();
    bf16x8 Ah[4], Al[4], Bh[4], Bl[4];
    #pragma unroll
    for (int tt = 0; tt < 4; ++tt){
      const u32* p = &Ws[(ow_ + tt * 16 + m) * 36 + q * 8];
      u32 w0=p[0],w1=p[1],w2=p[2],w3=p[3],w4=p[4],w5=p[5],w6=p[6],w7=p[7];
      Ah[tt] = s4_mk(S4_P16H(w1,w0), S4_P16H(w3,w2), S4_P16H(w5,w4), S4_P16H(w7,w6));
      Al[tt] = s4_mk(S4_P16L(w1,w0), S4_P16L(w3,w2), S4_P16L(w5,w4), S4_P16L(w7,w6));
    }
    #pragma unroll
    for (int uu = 0; uu < 4; ++uu){
      const u32* p = &Xs[(lw_ + uu * 16 + m) * 36 + q * 8];
      u32 w0=p[0],w1=p[1],w2=p[2],w3=p[3],w4=p[4],w5=p[5],w6=p[6],w7=p[7];
      Bh[uu] = s4_mk(S4_P16H(w1,w0), S4_P16H(w3,w2), S4_P16H(w5,w4), S4_P16H(w7,w6));
      Bl[uu] = s4_mk(S4_P16L(w1,w0), S4_P16L(w3,w2), S4_P16L(w5,w4), S4_P16L(w7,w6));
    }
    #pragma unroll
    for (int tt = 0; tt < 4; ++tt)
      #pragma unroll
      for (int uu = 0; uu < 4; ++uu){
        acc[tt][uu] = __builtin_amdgcn_mfma_f32_16x16x32_bf16(Ah[tt], Bh[uu], acc[tt][uu], 0, 0, 0);
        acc[tt][uu] = __builtin_amdgcn_mfma_f32_16x16x32_bf16(Al[tt], Bh[uu], acc[tt][uu], 0, 0, 0);
        acc[tt][uu] = __builtin_amdgcn_mfma_f32_16x16x32_bf16(Ah[tt], Bl[uu], acc[tt][uu], 0, 0, 0);
      }
    __syncthreads();
  }
  #pragma unroll
  for (int tt = 0; tt < 4; ++tt){
    #pragma unroll
    for (int uu = 0; uu < 4; ++uu){
      int l = l0 + lw_ + uu * 16 + m;
      #pragma unroll
      for (int r = 0; r < 4; ++r){
        int o = o0 + ow_ + tt * 16 + q * 4 + r;
        U[((size_t)b * 512 + o) * LSEQ + l] = gelu_f(acc[tt][uu][r] + bias[o]);
      }
    }
  }
}

// ================== S4 via MFMA (Toeplitz GEMM, split-bf16 x3) ==================
#define S4_SU 2464                    // u plane row stride (elements; [2432,2464) zeroed pad)
#define S4_UPLANE (8*S4_SU*2)         // 39424 B per plane
#define S4_ULO  S4_UPLANE             // u_lo plane offset
#define S4_REV  (2*S4_UPLANE)         // 78848
#define S4_TS   (S4_REV + 2856*4)     // 90272
#define S4_LDSZ (S4_TS + 8*576*4)     // 108704 (8 waves x 576-float transpose scratch)

// fill pipe slot SL with A frag-pair for current Wp (tile-top stream); Wp -= 32
#define S4_FILL(SL) { \
  int Wc = Wp > 0 ? Wp : 0; \
  int ib = rl + Wc; \
  u32 w0=RV[ib], w1=RV[ib+1], w2=RV[ib+2], w3=RV[ib+3], w4=RV[ib+4], w5=RV[ib+5], w6=RV[ib+6], w7=RV[ib+7]; \
  Ph[SL] = s4_mk(S4_P16H(w1,w0), S4_P16H(w3,w2), S4_P16H(w5,w4), S4_P16H(w7,w6)); \
  Pl[SL] = s4_mk(S4_P16L(w1,w0), S4_P16L(w3,w2), S4_P16L(w5,w4), S4_P16L(w7,w6)); \
  Wp -= 32; }

#define S4_MM(ph,d,BH,BL) \
  acc[d] = __builtin_amdgcn_mfma_f32_16x16x32_bf16(Ph[((ph)+5+(d))%12], BH, acc[d], 0, 0, 0); \
  acc[d] = __builtin_amdgcn_mfma_f32_16x16x32_bf16(Pl[((ph)+5+(d))%12], BH, acc[d], 0, 0, 0); \
  acc[d] = __builtin_amdgcn_mfma_f32_16x16x32_bf16(Ph[((ph)+5+(d))%12], BL, acc[d], 0, 0, 0);

// B prefetch: clamp >2400 first (A=0 beyond seq end), then j<0 -> zeroed pad at 2432.
#define S4_PHASE(ph,BC,BN) { \
  S4_FILL(((ph)+4)%12); \
  int bn = j0 - 32; bn = bn > 2400 ? 2400 : bn; bn = bn < 0 ? 2432 : bn; \
  const char* bp = LB + ubo + 2*bn; \
  Bh##BN = *(const bf16x8*)bp; \
  Bl##BN = *(const bf16x8*)(bp + S4_ULO); \
  S4_MM(ph,0,Bh##BC,Bl##BC) S4_MM(ph,1,Bh##BC,Bl##BC) S4_MM(ph,2,Bh##BC,Bl##BC) S4_MM(ph,3,Bh##BC,Bl##BC) \
  S4_MM(ph,4,Bh##BC,Bl##BC) S4_MM(ph,5,Bh##BC,Bl##BC) S4_MM(ph,6,Bh##BC,Bl##BC) S4_MM(ph,7,Bh##BC,Bl##BC) \
  j0 -= 32; }

// One workgroup (8 waves, 2/SIMD for latency hiding) per h. 20 chains of 8 tiles
// (l spaced 32), (g,half) jointly LPT-balanced across waves (max 144 phases/wave),
// via a 12-slot rotating A-frag pipe (load once per K-step, shared by all 8 tiles).
// N dim = batch (8 real cols, lanes 8..15 duplicate rows; never written).
// Tail phases (j0<0) read the zeroed B pad -> contribute exactly 0.
// krev staging fused in: RV[e] = packed hi|lo of k[2704-e] (0 outside [0,2432)).
__global__ __launch_bounds__(512, 1) void k_s4m(const float* __restrict__ ksrc,
    const float* __restrict__ Dv, const float* __restrict__ u, float* __restrict__ y){
  extern __shared__ char LB[];
  ushort* UH = (ushort*)LB;
  ushort* UL = (ushort*)(LB + S4_ULO);
  u32* RV = (u32*)(LB + S4_REV);
  int h = blockIdx.x;
  int tid = threadIdx.x;
  // ---- stage u rows (b=0..7) as bf16 hi/lo planes ----
  for (int e = tid; e < 8 * 608; e += 512){
    int b = e / 608, c4 = e % 608;
    float4 v = *(const float4*)(u + ((size_t)b * 512 + h) * 2432 + c4 * 4);
    u32 p0 = packsplit(v.x), p1 = packsplit(v.y), p2 = packsplit(v.z), p3 = packsplit(v.w);
    uint2 hw, lw;
    hw.x = (p0 & 0xffffu) | (p1 << 16);
    hw.y = (p2 & 0xffffu) | (p3 << 16);
    lw.x = (p0 >> 16) | (p1 & 0xffff0000u);
    lw.y = (p2 >> 16) | (p3 & 0xffff0000u);
    *(uint2*)(LB + (size_t)b * (S4_SU*2) + c4 * 8) = hw;
    *(uint2*)(LB + S4_ULO + (size_t)b * (S4_SU*2) + c4 * 8) = lw;
  }
  // ---- zero the 32-element tail pad of every u row (both planes) ----
  if (tid < 256){
    int b = tid >> 5, i = tid & 31;
    UH[b * S4_SU + 2432 + i] = 0;
    UL[b * S4_SU + 2432 + i] = 0;
  }
  // ---- stage reversed-k: pack hi|lo in-kernel (fused k_krev) ----
  {
    const float* kg = ksrc + (size_t)h * 2432;
    for (int e = tid; e < 2856; e += 512){
      u32 v = 0;
      int t = 2704 - e;
      if (t >= 0 && t < 2432) v = packsplit(kg[t]);
      RV[e] = v;
    }
  }
  __syncthreads();

  int lane = tid & 63;
  int wid = __builtin_amdgcn_readfirstlane(tid >> 6);
  int m = lane & 15, qq = lane >> 4;
  int rl = 16 - m + 8 * qq;                       // rev element base (lane const)
  int ubo = (m & 7) * (S4_SU*2) + qq * 16;        // byte offset in u plane
  float dv = Dv[h];
  float* TSp = (float*)(LB + S4_TS + wid * 2304);
  // chains encoded g*2+half; LPT partition (units of 12 phases): {12,12,11,11,11,11,11,11}
  static const signed char GC[8][5] = {
    {19,10,-1,-1,-1},{18,12,-1,-1,-1},{17, 8,-1,-1,-1},{15, 7,-1,-1,-1},
    {16,11,-1,-1,-1},{14, 9,-1,-1,-1},{13, 6, 4,-1,-1},{ 5, 3, 2, 1, 0}};

  #pragma unroll 1
  for (int c = 0; c < 5; ++c){
    int gc = GC[wid][c];
    if (gc < 0) break;
    int g = gc >> 1, half = gc & 1;
    int Lb = 256 * g + (half << 4);
    int ltop = Lb + 224;
    int J0 = ((ltop + 15) >> 5) << 5;
    int W0 = 2688 - ltop + J0;
    int NS = (J0 >> 5) + 1;
    int nIt = (NS + 11) / 12;

    f32x4 acc[8];
    bf16x8 Ph[12], Pl[12];
    bf16x8 Bh0, Bl0, Bh1, Bl1;
    {
      f32x4 za = {0.f, 0.f, 0.f, 0.f};
      acc[0]=za; acc[1]=za; acc[2]=za; acc[3]=za; acc[4]=za; acc[5]=za; acc[6]=za; acc[7]=za;
      bf16x8 zz = s4_mk(0u,0u,0u,0u);
      Ph[5]=zz; Ph[6]=zz; Ph[7]=zz; Ph[8]=zz; Ph[9]=zz; Ph[10]=zz; Ph[11]=zz; Ph[4]=zz;
      Pl[5]=zz; Pl[6]=zz; Pl[7]=zz; Pl[8]=zz; Pl[9]=zz; Pl[10]=zz; Pl[11]=zz; Pl[4]=zz;
    }
    int Wp = W0;
    S4_FILL(0) S4_FILL(1) S4_FILL(2) S4_FILL(3)
    int j0 = J0;
    {
      int bj0 = j0 > 2400 ? 2400 : j0;
      const char* bp0 = LB + ubo + 2 * bj0;
      Bh0 = *(const bf16x8*)bp0;
      Bl0 = *(const bf16x8*)(bp0 + S4_ULO);
    }
    #pragma unroll 1
    for (int it = 0; it < nIt; ++it){
      S4_PHASE(0,0,1) S4_PHASE(1,1,0) S4_PHASE(2,0,1) S4_PHASE(3,1,0)
      S4_PHASE(4,0,1) S4_PHASE(5,1,0) S4_PHASE(6,0,1) S4_PHASE(7,1,0)
      S4_PHASE(8,0,1) S4_PHASE(9,1,0) S4_PHASE(10,0,1) S4_PHASE(11,1,0)
    }
    // ---- epilogue: per-wave LDS transpose + D skip, coalesced y write ----
    #pragma unroll
    for (int d = 0; d < 8; ++d){
      int ld = Lb + 32 * d;
      if (ld < 2432){
        if (m < 8){
          TSp[(qq*4+0)*9 + m] = acc[d][0];
          TSp[(qq*4+1)*9 + m] = acc[d][1];
          TSp[(qq*4+2)*9 + m] = acc[d][2];
          TSp[(qq*4+3)*9 + m] = acc[d][3];
        }
        __builtin_amdgcn_wave_barrier();
        #pragma unroll
        for (int p = 0; p < 2; ++p){
          int li = lane & 15, bb = (lane >> 4) + 4 * p;
          float v = TSp[li*9 + bb];
          int l = ld + li;
          float uv = bfu2f(UH[bb * S4_SU + l]) + bfu2f(UL[bb * S4_SU + l]);
          y[((size_t)bb * 512 + h) * 2432 + l] = v + dv * uv;
        }
        __builtin_amdgcn_wave_barrier();
      }
    }
  }
}

// ---------- final LayerNorm over last dim (200) with transpose
__global__ __launch_bounds__(256) void k_ln(const float* __restrict__ o2,
    const float* __restrict__ lw, const float* __restrict__ lb2, float* __restrict__ out){
  __shared__ float s1[256], s2[256];
  int row = blockIdx.x;
  int b = row / 2432, l = row % 2432;
  int t = threadIdx.x;
  float v = 0.f;
  if (t < 200) v = o2[((size_t)b * 200 + t) * LSEQ + l];
  s1[t] = v; s2[t] = v * v;
  __syncthreads();
  for (int off = 128; off > 0; off >>= 1){
    if (t < off){ s1[t] += s1[t + off]; s2[t] += s2[t + off]; }
    __syncthreads();
  }
  float m = s1[0] * 0.005f;
  float var = s2[0] * 0.005f - m * m;
  float istd = rsqrtf(var + 1e-5f);
  if (t < 200) out[(size_t)row * 200 + t] = (v - m) * istd * lw[t] + lb2[t];
}

extern "C" void kernel_launch(void* const* d_in, const int* in_sizes, int n_in,
                              void* d_out, int out_size, void* d_ws, size_t ws_size,
                              hipStream_t stream){
  const float* x     = (const float*)d_in[0];
  const float* pe_w  = (const float*)d_in[1];
  const float* pe_b  = (const float*)d_in[2];
  const float* pi0_w = (const float*)d_in[3];
  const float* pi0_b = (const float*)d_in[4];
  const float* gn0_w = (const float*)d_in[5];
  const float* gn0_b = (const float*)d_in[6];
  const float* pi1_w = (const float*)d_in[7];
  const float* pi1_b = (const float*)d_in[8];
  const float* gn1_w = (const float*)d_in[9];
  const float* gn1_b = (const float*)d_in[10];
  const float* pi2_w = (const float*)d_in[11];
  const float* pi2_b = (const float*)d_in[12];
  const float* gn2_w = (const float*)d_in[13];
  const float* gn2_b = (const float*)d_in[14];
  const float* spec_w= (const float*)d_in[15];
  const float* spec_b= (const float*)d_in[16];
  const float* ic_w  = (const float*)d_in[17];
  const float* ic_b  = (const float*)d_in[18];
  const float* blk_sn= (const float*)d_in[19];
  const float* blk_cw= (const float*)d_in[20];
  const float* blk_cb= (const float*)d_in[21];
  const float* blk_k = (const float*)d_in[22];
  const float* blk_D = (const float*)d_in[23];
  const float* blk_ow= (const float*)d_in[24];
  const float* blk_ob= (const float*)d_in[25];
  const float* blk_Wv= (const float*)d_in[26];
  const float* blk_bv= (const float*)d_in[27];
  const float* blk_Wo= (const float*)d_in[28];
  const float* blk_bo= (const float*)d_in[29];
  const float* blk_rw= (const float*)d_in[30];
  const float* blk_rb= (const float*)d_in[31];
  const float* blk_sw= (const float*)d_in[32];
  const float* blk_sb= (const float*)d_in[33];
  const float* fc_w  = (const float*)d_in[34];
  const float* fc_b  = (const float*)d_in[35];
  const float* zc_w  = (const float*)d_in[36];
  const float* zc_b  = (const float*)d_in[37];
  const float* ln_w  = (const float*)d_in[38];
  const float* ln_b  = (const float*)d_in[39];

  // allow >64KB dynamic LDS for k_s4m (host-side, graph-capture safe)
  static int s4m_attr = 0;
  if (!s4m_attr){
    hipFuncSetAttribute(reinterpret_cast<const void*>(k_s4m),
                        hipFuncAttributeMaxDynamicSharedMemorySize, S4_LDSZ);
    s4m_attr = 1;
  }

  float* Wsp = (float*)d_ws;
  const size_t NLL = (size_t)8 * 256 * 2432;    // 4,980,736 floats
  float* noise = Wsp;                 // [0,1)
  float* hxb   = Wsp + NLL;           // [1,2)
  float* skb   = Wsp + 2 * NLL;       // [2,3)
  float* ub    = Wsp + 3 * NLL;       // [3,5)  u / v / a / fc-out
  float* ysb   = Wsp + 5 * NLL;       // [5,7)  s4-out per s / ht / zc-out
  float* htb   = ysb;
  unsigned short* actT = (unsigned short*)(Wsp + 7 * NLL);   // [7,11) bf16 [b][l][2048]
  unsigned short* wB = (unsigned short*)(Wsp + 11 * NLL);
  unsigned short* owB = wB;                    // 6*1024*2048 = 12,582,912
  unsigned short* WvB = wB + 12582912;         // 1,572,864
  unsigned short* WoB = wB + 14155776;         // 1,572,864
  unsigned short* rwB = wB + 15728640;         // 393,216
  unsigned short* swB = wB + 16121856;         // 393,216
  unsigned short* icB = wB + 16515072;         // 57,344
  unsigned short* fcB = wB + 16572416;         // 65,536
  unsigned short* zcB = wB + 16637952;         // 51,200 -> end 16,689,152 ushorts
  float* rinv   = Wsp + 11 * NLL + 8344576;    // 19,456 floats
  float* gnstats= rinv + 19456;                // 80 floats
  u32* WpB = (u32*)(Wsp + 63152208);           // conv3 packed W: 393,216 dwords (old krev region)
  u32* XpT = (u32*)(Wsp + 7 * NLL);            // conv3 packed X: 4,980,736 dwords (actT region, dead then)

  // front-end aliases (regions dead at that point)
  float* p0 = ub;
  float* p1 = ysb;
  float* p2 = ub;
  float* pe = Wsp + 7 * NLL;          // actT region (floats), dead before first castT use
  float* spec = Wsp + 8 * NLL;
  float* peT = skb;                   // skb garbage OK (first sw gemm accf=0)
  float* hb = hxb;                    // overwritten later by memcpy noise->hxb

  const float SQ05 = 0.70710678118654752440f;
  const float SQ16 = 0.40824829046386301637f;

  // ---- weight casts (bf16) ----
  k_wcast_glu<<<49152,256,0,stream>>>(blk_ow, owB);
  k_wcast<<<(3072*512+255)/256,256,0,stream>>>(blk_Wv, WvB, 3072, 512, 512);
  k_wcast<<<(3072*512+255)/256,256,0,stream>>>(blk_Wo, WoB, 3072, 512, 512);
  k_wcast<<<(1536*256+255)/256,256,0,stream>>>(blk_rw, rwB, 1536, 256, 256);
  k_wcast<<<(1536*256+255)/256,256,0,stream>>>(blk_sw, swB, 1536, 256, 256);
  k_wcast<<<(256*224+255)/256,256,0,stream>>>(ic_w, icB, 256, 200, 224);
  k_wcast<<<(256*256+255)/256,256,0,stream>>>(fc_w, fcB, 256, 256, 256);
  k_wcast<<<(200*256+255)/256,256,0,stream>>>(zc_w, zcB, 200, 256, 256);

  // ---- PatchEmbedding ----
  k_pi0b<<<dim3(76,8), 256, 0, stream>>>(x, pi0_w, pi0_b, p0);
  k_gn_reduce<<<40,256,0,stream>>>(p0, gnstats);
  k_gn_apply<<<15200,256,0,stream>>>(p0, gnstats, gn0_w, gn0_b);
  k_pconv3b<<<dim3(76,8),256,0,stream>>>(p0, pi1_w, pi1_b, p1);
  k_gn_reduce<<<40,256,0,stream>>>(p1, gnstats);
  k_gn_apply<<<15200,256,0,stream>>>(p1, gnstats, gn1_w, gn1_b);
  k_pconv3b<<<dim3(76,8),256,0,stream>>>(p1, pi2_w, pi2_b, p2);
  k_gn_reduce<<<40,256,0,stream>>>(p2, gnstats);
  k_gn_apply<<<15200,256,0,stream>>>(p2, gnstats, gn2_w, gn2_b);
  k_pe_build<<<15200,256,0,stream>>>(p2, pe);
  k_spec<<<19456,256,0,stream>>>(x, spec);
  k_spec_mm<<<19456,256,0,stream>>>(spec, spec_w, spec_b, pe);
  k_trp<<<dim3(76,7,8),256,0,stream>>>(pe, peT);
  k_hbuild2<<<dim3(19,200,8),128,0,stream>>>(peT, pe_w, pe_b, hb);
  k_castT<<<dim3(76,7,8),256,0,stream>>>(hb, actT, 200, 224, 0);
  k_bgemm<<<dim3(19,2,8),256,0,stream>>>(icB, actT, ic_b, nullptr, nullptr, nullptr,
                                         noise, 256, 224, 1.f, 1.f, 1, 0);
  hipMemcpyAsync(hxb, noise, NLL * sizeof(float), hipMemcpyDeviceToDevice, stream);

  // ---- residual blocks ----
  for (int i = 0; i < 6; ++i){
    const float* sn = blk_sn + i * 256;
    const float* cw = blk_cw + (size_t)i * 512 * 768;
    const float* cb = blk_cb + i * 512;
    const float* ob = blk_ob + i * 1024;
    const float* bv = blk_bv + i * 512;
    const float* bo = blk_bo + i * 512;
    const float* rb = blk_rb + i * 256;
    const float* sb = blk_sb + i * 256;

    k_rmsr<<<76,256,0,stream>>>(hxb, rinv);
    // conv3 via MFMA: pack X (hx+noise, transposed) and W, then GEMM
    k_packT<<<dim3(76,8,8),256,0,stream>>>(hxb, noise, XpT);
    k_wpack3<<<1536,256,0,stream>>>(cw, WpB);
    k_conv3m<<<dim3(19,4,8),256,0,stream>>>(WpB, cb, XpT, ub);
    for (int s = 0; s < 4; ++s){
      const float* kw = blk_k + ((size_t)i * 4 + s) * 512 * 2432;
      const float* Dvp = blk_D + ((size_t)i * 4 + s) * 512;
      k_s4m<<<dim3(512),512,S4_LDSZ,stream>>>(kw, Dvp, ub, ysb);
      k_castT<<<dim3(76,16,8),256,0,stream>>>(ysb, actT, 512, 2048, s * 512);
    }
    // fused ow-GEMM + GLU -> ht (512 ch)
    k_bgemm<<<dim3(19,8,8),256,0,stream>>>(owB + (size_t)i*1024*2048, actT, ob,
                                           nullptr, nullptr, nullptr, htb,
                                           1024, 2048, 1.f, 1.f, 3, 0);
    k_castT<<<dim3(76,16,8),256,0,stream>>>(htb, actT, 512, 512, 0);
    k_bgemm<<<dim3(19,4,8),256,0,stream>>>(WvB + (size_t)i*512*512, actT, bv,
                                           nullptr, nullptr, nullptr, ub,
                                           512, 512, 1.f, 1.f, 0, 0);
    k_castT<<<dim3(76,16,8),256,0,stream>>>(ub, actT, 512, 512, 0);
    k_bgemm<<<dim3(19,4,8),256,0,stream>>>(WoB + (size_t)i*512*512, actT, bo,
                                           nullptr, nullptr, nullptr, ub,
                                           512, 512, 1.f, 1.f, 0, 0);
    k_gateT<<<dim3(76,8,8),256,0,stream>>>(htb, ub, actT);
    // rw-GEMM with fused RMS residual: hx = (sn*hx*rinv + rw@out + rb)*sqrt(0.5)
    k_bgemm<<<dim3(19,2,8),256,0,stream>>>(rwB + (size_t)i*256*256, actT, rb,
                                           hxb, sn, rinv, hxb,
                                           256, 256, 1.f, SQ05, 0, 0);
    k_bgemm<<<dim3(19,2,8),256,0,stream>>>(swB + (size_t)i*256*256, actT, sb,
                                           nullptr, nullptr, nullptr, skb,
                                           256, 256, 1.f, 1.f, 0, i==0?0:1);
  }

  // ---- tail ----
  k_castT<<<dim3(76,8,8),256,0,stream>>>(skb, actT, 256, 256, 0);
  k_bgemm<<<dim3(19,2,8),256,0,stream>>>(fcB, actT, fc_b, nullptr, nullptr, nullptr,
                                         ub, 256, 256, SQ16, 1.f, 1, 0);
  k_castT<<<dim3(76,8,8),256,0,stream>>>(ub, actT, 256, 256, 0);
  k_bgemm<<<dim3(19,2,8),256,0,stream>>>(zcB, actT, zc_b, nullptr, nullptr, nullptr,
                                         ysb, 200, 256, 1.f, 1.f, 0, 0);
  k_ln<<<19456,256,0,stream>>>(ysb, ln_w, ln_b, (float*)d_out);
}

// Round 7
// 7990.378 us; speedup vs baseline: 2.4418x; 1.0551x over previous
//
#include <hip/hip_runtime.h>
#include <hip/hip_bf16.h>
#include <math.h>

#define LSEQ 2432

typedef short bf16x8 __attribute__((ext_vector_type(8)));
typedef float f32x4 __attribute__((ext_vector_type(4)));
typedef unsigned int u32;

__device__ __forceinline__ float gelu_f(float x){
  return 0.5f * x * (1.0f + erff(x * 0.70710678118654752440f));
}
__device__ __forceinline__ float sigmoid_f(float x){
  return 1.0f / (1.0f + __expf(-x));
}
__device__ __forceinline__ unsigned short f2bf(float f){
  __hip_bfloat16 h = __float2bfloat16(f);   // RNE
  return *reinterpret_cast<unsigned short*>(&h);
}
__device__ __forceinline__ float bfu2f(unsigned short s){
  union { u32 u; float f; } X; X.u = ((u32)s) << 16; return X.f;
}
// split f32 -> (hi bf16 in low16, lo bf16 in high16)
__device__ __forceinline__ u32 packsplit(float v){
  unsigned short hi = f2bf(v);
  float lo = v - bfu2f(hi);
  unsigned short ls = f2bf(lo);
  return (u32)hi | ((u32)ls << 16);
}
// async global->LDS 16B per lane (dest = uniform base + lane*16)
__device__ __forceinline__ void gload16(const void* gsrc, void* ldsdst){
  __builtin_amdgcn_global_load_lds(
      (const __attribute__((address_space(1))) unsigned int*)gsrc,
      (__attribute__((address_space(3))) unsigned int*)ldsdst,
      16, 0, 0);
}

// ---------- pi0 (LDS-staged): block = 32 rows x 1 batch; thread = (row,wv); loop o
__global__ __launch_bounds__(256) void k_pi0b(const float* __restrict__ x,
    const float* __restrict__ w, const float* __restrict__ bias,
    float* __restrict__ out){
  __shared__ float xs[32][200];
  __shared__ float ws[25][49];
  __shared__ float bs[25];
  int r0 = blockIdx.x * 32, b = blockIdx.y;
  int tid = threadIdx.x;
  const float* xb = x + ((size_t)b * 2432 + r0) * 200;
  for (int e = tid; e < 1600; e += 256){
    int row = e / 50, c4 = e % 50;
    *(float4*)&xs[row][c4 * 4] = *(const float4*)(xb + row * 200 + c4 * 4);
  }
  for (int e = tid; e < 1225; e += 256) ws[e / 49][e % 49] = w[e];
  if (tid < 25) bs[tid] = bias[tid];
  __syncthreads();
  int row = tid >> 3, wv = tid & 7;
  int start = wv * 25 - 24;
  float tap[49];
  #pragma unroll
  for (int t = 0; t < 49; ++t){
    int ix = start + t;
    tap[t] = (ix >= 0 && ix < 200) ? xs[row][ix] : 0.f;
  }
  for (int o = 0; o < 25; ++o){
    float acc = bs[o];
    #pragma unroll
    for (int t = 0; t < 49; ++t) acc += tap[t] * ws[o][t];
    out[(((size_t)b * 25 + o) * 2432 + (r0 + row)) * 8 + wv] = acc;
  }
}

// ---------- group norm (groups=5 over 25 ch)
__global__ __launch_bounds__(256) void k_gn_reduce(const float* __restrict__ p, float* __restrict__ stats){
  int b = blockIdx.x / 5, g = blockIdx.x % 5;
  const float* base = p + ((size_t)b * 25 + g * 5) * 19456;
  float s = 0.f, s2 = 0.f;
  for (int i = threadIdx.x; i < 97280; i += 256){ float v = base[i]; s += v; s2 += v * v; }
  __shared__ float sh[256], sh2[256];
  int t = threadIdx.x;
  sh[t] = s; sh2[t] = s2; __syncthreads();
  for (int off = 128; off > 0; off >>= 1){
    if (t < off){ sh[t] += sh[t+off]; sh2[t] += sh2[t+off]; }
    __syncthreads();
  }
  if (t == 0){
    float m = sh[0] / 97280.f;
    float var = sh2[0] / 97280.f - m * m;
    stats[blockIdx.x * 2] = m;
    stats[blockIdx.x * 2 + 1] = rsqrtf(var + 1e-5f);
  }
}

__global__ __launch_bounds__(256) void k_gn_apply(float* __restrict__ p, const float* __restrict__ stats,
    const float* __restrict__ gw, const float* __restrict__ gb){
  size_t i = (size_t)blockIdx.x * 256 + threadIdx.x;
  int c = (int)((i / 19456) % 25);
  int b = (int)(i / 486400);
  int g = c / 5;
  float m = stats[(b*5+g)*2], istd = stats[(b*5+g)*2+1];
  float v = (p[i] - m) * istd * gw[c] + gb[c];
  p[i] = gelu_f(v);
}

// ---------- pconv3 (LDS-staged): block = 32 rows x 1 batch; thread = (row,wv); loop o
__global__ __launch_bounds__(256) void k_pconv3b(const float* __restrict__ pin,
    const float* __restrict__ w, const float* __restrict__ bias, float* __restrict__ pout){
  __shared__ float T[25][256];    // [i][row*8+wv]
  __shared__ float ws[25][75];
  __shared__ float bs[25];
  int r0 = blockIdx.x * 32, b = blockIdx.y;
  int tid = threadIdx.x;
  const float* pb = pin + (size_t)b * 25 * 19456 + r0 * 8;
  for (int e = tid; e < 25 * 64; e += 256){
    int i = e / 64, c4 = e % 64;
    *(float4*)&T[i][c4 * 4] = *(const float4*)(pb + (size_t)i * 19456 + c4 * 4);
  }
  for (int e = tid; e < 1875; e += 256) ws[e / 75][e % 75] = w[e];
  if (tid < 25) bs[tid] = bias[tid];
  __syncthreads();
  int wv = tid & 7;
  float xm[25], x0[25], xp[25];
  #pragma unroll
  for (int i = 0; i < 25; ++i){
    x0[i] = T[i][tid];
    xm[i] = (wv > 0) ? T[i][tid - 1] : 0.f;
    xp[i] = (wv < 7) ? T[i][tid + 1] : 0.f;
  }
  for (int o = 0; o < 25; ++o){
    float acc = bs[o];
    #pragma unroll
    for (int i = 0; i < 25; ++i)
      acc += xm[i] * ws[o][i*3] + x0[i] * ws[o][i*3+1] + xp[i] * ws[o][i*3+2];
    pout[(((size_t)b * 25 + o) * 2432 + r0) * 8 + tid] = acc;
  }
}

// ---------- pe[b,l,p] = p2[b, p>>3, l, p&7]
__global__ __launch_bounds__(256) void k_pe_build(const float* __restrict__ p2, float* __restrict__ pe){
  size_t i = (size_t)blockIdx.x * 256 + threadIdx.x;
  int p = (int)(i % 200);
  size_t rem = i / 200;
  int l = (int)(rem % 2432);
  int b = (int)(rem / 2432);
  pe[i] = p2[(((size_t)b*25 + (p>>3)) * 2432 + l) * 8 + (p & 7)];
}

// ---------- spec = |DFT_200(x)| / 200  (101 bins)
__global__ __launch_bounds__(256) void k_spec(const float* __restrict__ x, float* __restrict__ spec){
  __shared__ float xr[200], ct[200], st[200];
  int row = blockIdx.x;
  int t = threadIdx.x;
  if (t < 200){
    xr[t] = x[(size_t)row * 200 + t];
    float ang = -0.031415926535897932385f * t;
    ct[t] = cosf(ang); st[t] = sinf(ang);
  }
  __syncthreads();
  if (t < 101){
    float re = 0.f, im = 0.f;
    int ph = 0;
    for (int k = 0; k < 200; ++k){
      re += xr[k] * ct[ph];
      im += xr[k] * st[ph];
      ph += t; if (ph >= 200) ph -= 200;
    }
    spec[(size_t)row * 101 + t] = sqrtf(re*re + im*im) * 0.005f;
  }
}

// ---------- pe += spec @ spec_w^T + spec_b
__global__ __launch_bounds__(256) void k_spec_mm(const float* __restrict__ spec,
    const float* __restrict__ sw, const float* __restrict__ sb, float* __restrict__ pe){
  __shared__ float sr[101];
  int row = blockIdx.x;
  int t = threadIdx.x;
  if (t < 101) sr[t] = spec[(size_t)row * 101 + t];
  __syncthreads();
  if (t < 200){
    const float* wr = sw + t * 101;
    float acc = sb[t];
    for (int f = 0; f < 101; ++f) acc += sr[f] * wr[f];
    pe[(size_t)row * 200 + t] += acc;
  }
}

// ---------- pe (b,L,200) -> peT (b,200,L), 32x32 LDS tiles
__global__ __launch_bounds__(256) void k_trp(const float* __restrict__ pe, float* __restrict__ peT){
  __shared__ float ts[32][33];
  int l0 = blockIdx.x * 32, c0 = blockIdx.y * 32, b = blockIdx.z;
  int t = threadIdx.x;
  int i = t >> 5, j = t & 31;
  #pragma unroll
  for (int pass = 0; pass < 4; ++pass){
    int ii = i + pass * 8;
    int c = c0 + j;
    ts[ii][j] = (c < 200) ? pe[((size_t)b * 2432 + l0 + ii) * 200 + c] : 0.f;
  }
  __syncthreads();
  #pragma unroll
  for (int pass = 0; pass < 4; ++pass){
    int ii = i + pass * 8;
    int c = c0 + ii;
    if (c < 200) peT[((size_t)b * 200 + c) * 2432 + l0 + j] = ts[j][ii];
  }
}

// ---------- hbuild: h[b,p,c*128+j] = peT[b,p,c*128+j] + depthwise19x7 conv
__global__ __launch_bounds__(128) void k_hbuild2(const float* __restrict__ peT,
    const float* __restrict__ pw, const float* __restrict__ pb, float* __restrict__ h){
  __shared__ float T[19][136];
  __shared__ float wsh[133];
  int c = blockIdx.x, p = blockIdx.y, b = blockIdx.z;
  int tid = threadIdx.x;
  const float* pr = peT + ((size_t)b * 200 + p) * 2432;
  for (int e = tid; e < 19 * 136; e += 128){
    int a = e / 136, m = e % 136;
    int hh = c - 9 + a, ww = m - 3;
    float v = 0.f;
    if (hh >= 0 && hh < 19 && ww >= 0 && ww < 128) v = pr[hh * 128 + ww];
    T[a][m] = v;
  }
  for (int e = tid; e < 133; e += 128) wsh[e] = pw[p * 133 + e];
  __syncthreads();
  int j = tid;
  float conv = pb[p];
  #pragma unroll
  for (int a = 0; a < 19; ++a){
    #pragma unroll
    for (int tt = 0; tt < 7; ++tt) conv += T[a][j + tt] * wsh[a * 7 + tt];
  }
  float orig = T[9][j + 3];
  h[((size_t)b * 200 + p) * 2432 + c * 128 + j] = orig + conv;
}

// ---------- weight cast f32 [O][Kin] -> bf16 [O][Kpad] (zero pad)
__global__ __launch_bounds__(256) void k_wcast(const float* __restrict__ src,
    unsigned short* __restrict__ dst, int O, int Kin, int Kpad){
  size_t i = (size_t)blockIdx.x * 256 + threadIdx.x;
  if (i >= (size_t)O * Kpad) return;
  int k = (int)(i % Kpad);
  int o = (int)(i / Kpad);
  dst[i] = (k < Kin) ? f2bf(src[(size_t)o * Kin + k]) : 0;
}

// ---------- ow cast with GLU row interleave: dst row ro <- src row (ro>>1)+(ro&1)*512
__global__ __launch_bounds__(256) void k_wcast_glu(const float* __restrict__ src,
    unsigned short* __restrict__ dst){
  size_t i = (size_t)blockIdx.x * 256 + threadIdx.x;
  if (i >= (size_t)6 * 1024 * 2048) return;
  int k = (int)(i % 2048);
  size_t rem = i / 2048;
  int ro = (int)(rem % 1024);
  int blk = (int)(rem / 1024);
  int j = (ro >> 1) + (ro & 1) * 512;
  dst[i] = f2bf(src[((size_t)blk * 1024 + j) * 2048 + k]);
}

// ---------- cast+transpose f32 [b][C][L] -> bf16 [b][L][Kpad] cols [cbase, cbase+C)
__global__ __launch_bounds__(256) void k_castT(const float* __restrict__ in,
    unsigned short* __restrict__ out, int C, int Kpad, int cbase){
  __shared__ float ts[32][33];
  int l0 = blockIdx.x * 32, c0 = blockIdx.y * 32, b = blockIdx.z;
  int t = threadIdx.x;
  int i = t >> 5, j = t & 31;
  #pragma unroll
  for (int pass = 0; pass < 4; ++pass){
    int ci = c0 + i + pass * 8;
    ts[i + pass * 8][j] = (ci < C) ? in[((size_t)b * C + ci) * LSEQ + l0 + j] : 0.f;
  }
  __syncthreads();
  #pragma unroll
  for (int pass = 0; pass < 4; ++pass){
    int li = l0 + i + pass * 8;
    out[((size_t)b * LSEQ + li) * Kpad + cbase + c0 + j] = f2bf(ts[j][i + pass * 8]);
  }
}

// ---------- pack+transpose (hx+noise) f32 [b][256][L] -> u32 hi|lo [b][L][256]
__global__ __launch_bounds__(256) void k_packT(const float* __restrict__ A,
    const float* __restrict__ N, u32* __restrict__ out){
  __shared__ float ts[32][33];
  int l0 = blockIdx.x * 32, c0 = blockIdx.y * 32, b = blockIdx.z;
  int t = threadIdx.x;
  int i = t >> 5, j = t & 31;
  #pragma unroll
  for (int pass = 0; pass < 4; ++pass){
    int ci = c0 + i + pass * 8;
    size_t ii = ((size_t)b * 256 + ci) * LSEQ + l0 + j;
    ts[i + pass * 8][j] = A[ii] + N[ii];
  }
  __syncthreads();
  #pragma unroll
  for (int pass = 0; pass < 4; ++pass){
    int li = l0 + i + pass * 8;
    out[((size_t)b * LSEQ + li) * 256 + c0 + j] = packsplit(ts[j][i + pass * 8]);
  }
}

// ---------- pack conv3 weights: Wp[o][t*256+c] = packsplit(cw[o][c][t])
__global__ __launch_bounds__(256) void k_wpack3(const float* __restrict__ cw, u32* __restrict__ Wp){
  int i = blockIdx.x * 256 + threadIdx.x;     // 512*768
  int o = i / 768, rem = i % 768;
  int t = rem / 256, c = rem % 256;
  Wp[i] = packsplit(cw[((size_t)o * 256 + c) * 3 + t]);
}

// ---------- gate fused with cast+transpose: actT[b][l][c] = bf16(tanh(g1)*sigmoid(g2))
__global__ __launch_bounds__(256) void k_gateT(const float* __restrict__ ht,
    const float* __restrict__ a, unsigned short* __restrict__ out){
  __shared__ float ts[32][33];
  int l0 = blockIdx.x * 32, c0 = blockIdx.y * 32, b = blockIdx.z;
  int t = threadIdx.x;
  int i = t >> 5, j = t & 31;
  #pragma unroll
  for (int pass = 0; pass < 4; ++pass){
    int ci = c0 + i + pass * 8;
    size_t i1 = ((size_t)b * 512 + ci) * LSEQ + l0 + j;
    size_t i2 = ((size_t)b * 512 + ci + 256) * LSEQ + l0 + j;
    float g1 = ht[i1] + a[i1];
    float g2 = ht[i2] + a[i2];
    ts[i + pass * 8][j] = tanhf(g1) * sigmoid_f(g2);
  }
  __syncthreads();
  #pragma unroll
  for (int pass = 0; pass < 4; ++pass){
    int li = l0 + i + pass * 8;
    out[((size_t)b * LSEQ + li) * 256 + c0 + j] = f2bf(ts[j][i + pass * 8]);
  }
}

// ---------- rms inverse scale per (b,l)
__global__ __launch_bounds__(256) void k_rmsr(const float* __restrict__ hx, float* __restrict__ rinv){
  int idx = blockIdx.x * 256 + threadIdx.x;   // 19456
  int b = idx / 2432, l = idx % 2432;
  const float* p = hx + (size_t)b * 256 * LSEQ + l;
  float s = 0.f;
  #pragma unroll 8
  for (int c = 0; c < 256; ++c){ float v = p[(size_t)c * LSEQ]; s += v * v; }
  rinv[idx] = 1.0f / (sqrtf(s * (1.0f/256.0f)) + 1e-8f);
}

// ---------- bf16 MFMA GEMM (global_load_lds staging, XOR chunk swizzle, conflict-free).
// LDS tile: [128 rows][32 ushorts], chunk c of row r stored at chunk c^(r&3).
// act: 0 none, 1 relu, 3 GLU(pair rows -> out has O/2=512 rows)
// res2 mode (sn!=nullptr): v += sn[o]*res[oi]*rinv[b*2432+l]
__global__ __launch_bounds__(256) void k_bgemm(const unsigned short* __restrict__ Wb,
    const unsigned short* __restrict__ Xb, const float* __restrict__ bias,
    const float* __restrict__ res, const float* __restrict__ sn,
    const float* __restrict__ rinv, float* __restrict__ out,
    int O, int Kpad, float alpha, float fs, int act, int accf){
  __shared__ unsigned short Ws[128 * 32];
  __shared__ unsigned short Xs[128 * 32];
  int l0 = blockIdx.x * 128, o0 = blockIdx.y * 128, b = blockIdx.z;
  int tid = threadIdx.x;
  int w = tid >> 6, lane = tid & 63;
  int ow_ = (w & 1) * 64, lw_ = (w >> 1) * 64;
  int m = lane & 15, q = (lane >> 4) & 3;
  int lrow = lane >> 2;                       // 0..15 within segment
  int csw = (lane & 3) ^ (lrow & 3);          // swizzled source chunk
  int rsw = (q ^ (m & 3)) * 8;                // swizzled read chunk offset (ushorts)
  const unsigned short* Xbb = Xb + (size_t)b * 2432 * Kpad;
  f32x4 acc[4][4] = {};
  for (int k0 = 0; k0 < Kpad; k0 += 32){
    #pragma unroll
    for (int r = 0; r < 2; ++r){
      int seg = w * 2 + r;
      int row = seg * 16 + lrow;
      int oc = o0 + row; if (oc >= O) oc = O - 1;   // clamp (garbage rows never written out)
      gload16(Wb + (size_t)oc * Kpad + k0 + csw * 8, &Ws[seg * 512]);
      gload16(Xbb + (size_t)(l0 + row) * Kpad + k0 + csw * 8, &Xs[seg * 512]);
    }
    __syncthreads();
    bf16x8 A[4], Bf[4];
    #pragma unroll
    for (int t = 0; t < 4; ++t) A[t] = *(const bf16x8*)&Ws[(ow_ + t * 16 + m) * 32 + rsw];
    #pragma unroll
    for (int u = 0; u < 4; ++u) Bf[u] = *(const bf16x8*)&Xs[(lw_ + u * 16 + m) * 32 + rsw];
    #pragma unroll
    for (int t = 0; t < 4; ++t)
      #pragma unroll
      for (int u = 0; u < 4; ++u)
        acc[t][u] = __builtin_amdgcn_mfma_f32_16x16x32_bf16(A[t], Bf[u], acc[t][u], 0, 0, 0);
    __syncthreads();
  }
  if (act == 3){
    // GLU: reordered rows; pair (even reg r, odd reg r+1); ht row = ro>>1
    #pragma unroll
    for (int t = 0; t < 4; ++t){
      #pragma unroll
      for (int u = 0; u < 4; ++u){
        int l = l0 + lw_ + u * 16 + m;
        #pragma unroll
        for (int r = 0; r < 4; r += 2){
          int ro = o0 + ow_ + t * 16 + q * 4 + r;    // even
          int j = ro >> 1;
          float v1 = acc[t][u][r]   + bias[j];
          float v2 = acc[t][u][r+1] + bias[j + 512];
          out[((size_t)b * 512 + j) * LSEQ + l] = v1 * sigmoid_f(v2);
        }
      }
    }
    return;
  }
  #pragma unroll
  for (int t = 0; t < 4; ++t){
    #pragma unroll
    for (int u = 0; u < 4; ++u){
      int l = l0 + lw_ + u * 16 + m;
      #pragma unroll
      for (int r = 0; r < 4; ++r){
        int o = o0 + ow_ + t * 16 + q * 4 + r;
        if (o >= O) continue;
        size_t oi = ((size_t)b * O + o) * LSEQ + l;
        float v = alpha * acc[t][u][r];
        if (bias) v += bias[o];
        if (res){
          if (sn) v += sn[o] * res[oi] * rinv[b * 2432 + l];
          else v += res[oi];
        }
        if (accf) v += out[oi];
        if (act == 1) v = fmaxf(v, 0.f);
        out[oi] = v * fs;
      }
    }
  }
}

__device__ __forceinline__ bf16x8 s4_mk(u32 a, u32 b, u32 c, u32 d){
  union { u32 u[4]; bf16x8 v; } X; X.u[0]=a; X.u[1]=b; X.u[2]=c; X.u[3]=d; return X.v;
}
#define S4_P16H(a,b) __builtin_amdgcn_perm((a),(b),0x05040100u)
#define S4_P16L(a,b) __builtin_amdgcn_perm((a),(b),0x07060302u)

// ---------- conv3 via MFMA: u = gelu(conv1d(hx+noise, cw(512,256,3), cb, pad1))
// split-bf16 x3 (fp32-class). Wp: u32 hi|lo [512][768] (t-major). Xp: u32 hi|lo [b][2432][256].
__global__ __launch_bounds__(256) void k_conv3m(const u32* __restrict__ Wp,
    const float* __restrict__ bias, const u32* __restrict__ Xp, float* __restrict__ U){
  __shared__ u32 Ws[128 * 36];
  __shared__ u32 Xs[128 * 36];
  int l0 = blockIdx.x * 128, o0 = blockIdx.y * 128, b = blockIdx.z;
  int tid = threadIdx.x;
  int w = tid >> 6, lane = tid & 63;
  int ow_ = (w & 1) * 64, lw_ = (w >> 1) * 64;
  int m = lane & 15, q = (lane >> 4) & 3;
  const u32* Xb = Xp + (size_t)b * 2432 * 256;
  f32x4 acc[4][4] = {};
  for (int s = 0; s < 24; ++s){
    int t = s >> 3, k0 = (s & 7) << 5;
    #pragma unroll
    for (int r = 0; r < 4; ++r){
      int idx = tid + r * 256;                 // 0..1023
      int row = idx >> 3, cq = (idx & 7) * 4;  // 128 rows x 8 chunks of 4 u32
      *(uint4*)&Ws[row * 36 + cq] = *(const uint4*)(Wp + (size_t)(o0 + row) * 768 + t * 256 + k0 + cq);
      int li = l0 + row + t - 1;
      uint4 xv = make_uint4(0u, 0u, 0u, 0u);
      if (li >= 0 && li < 2432) xv = *(const uint4*)(Xb + (size_t)li * 256 + k0 + cq);
      *(uint4*)&Xs[row * 36 + cq] = xv;
    }
    __syncthreads();
    bf16x8 Ah[4], Al[4], Bh[4], Bl[4];
    #pragma unroll
    for (int tt = 0; tt < 4; ++tt){
      const u32* p = &Ws[(ow_ + tt * 16 + m) * 36 + q * 8];
      u32 w0=p[0],w1=p[1],w2=p[2],w3=p[3],w4=p[4],w5=p[5],w6=p[6],w7=p[7];
      Ah[tt] = s4_mk(S4_P16H(w1,w0), S4_P16H(w3,w2), S4_P16H(w5,w4), S4_P16H(w7,w6));
      Al[tt] = s4_mk(S4_P16L(w1,w0), S4_P16L(w3,w2), S4_P16L(w5,w4), S4_P16L(w7,w6));
    }
    #pragma unroll
    for (int uu = 0; uu < 4; ++uu){
      const u32* p = &Xs[(lw_ + uu * 16 + m) * 36 + q * 8];
      u32 w0=p[0],w1=p[1],w2=p[2],w3=p[3],w4=p[4],w5=p[5],w6=p[6],w7=p[7];
      Bh[uu] = s4_mk(S4_P16H(w1,w0), S4_P16H(w3,w2), S4_P16H(w5,w4), S4_P16H(w7,w6));
      Bl[uu] = s4_mk(S4_P16L(w1,w0), S4_P16L(w3,w2), S4_P16L(w5,w4), S4_P16L(w7,w6));
    }
    #pragma unroll
    for (int tt = 0; tt < 4; ++tt)
      #pragma unroll
      for (int uu = 0; uu < 4; ++uu){
        acc[tt][uu] = __builtin_amdgcn_mfma_f32_16x16x32_bf16(Ah[tt], Bh[uu], acc[tt][uu], 0, 0, 0);
        acc[tt][uu] = __builtin_amdgcn_mfma_f32_16x16x32_bf16(Al[tt], Bh[uu], acc[tt][uu], 0, 0, 0);
        acc[tt][uu] = __builtin_amdgcn_mfma_f32_16x16x32_bf16(Ah[tt], Bl[uu], acc[tt][uu], 0, 0, 0);
      }
    __syncthreads();
  }
  #pragma unroll
  for (int tt = 0; tt < 4; ++tt){
    #pragma unroll
    for (int uu = 0; uu < 4; ++uu){
      int l = l0 + lw_ + uu * 16 + m;
      #pragma unroll
      for (int r = 0; r < 4; ++r){
        int o = o0 + ow_ + tt * 16 + q * 4 + r;
        U[((size_t)b * 512 + o) * LSEQ + l] = gelu_f(acc[tt][uu][r] + bias[o]);
      }
    }
  }
}

// ================== S4 via MFMA (Toeplitz GEMM, split-bf16 x3) ==================
#define S4_SU 2464                    // u plane row stride (elements; [2432,2464) zeroed pad)
#define S4_UPLANE (8*S4_SU*2)         // 39424 B per plane
#define S4_ULO  S4_UPLANE             // u_lo plane offset
#define S4_REV  (2*S4_UPLANE)         // 78848
#define S4_TS   (S4_REV + 2856*4)     // 90272
#define S4_LDSZ (S4_TS + 8*576*4)     // 108704 (8 waves x 576-float transpose scratch)

// fill pipe slot SL with A frag-pair for current Wp (tile-top stream); Wp -= 32
#define S4_FILL(SL) { \
  int Wc = Wp > 0 ? Wp : 0; \
  int ib = rl + Wc; \
  u32 w0=RV[ib], w1=RV[ib+1], w2=RV[ib+2], w3=RV[ib+3], w4=RV[ib+4], w5=RV[ib+5], w6=RV[ib+6], w7=RV[ib+7]; \
  Ph[SL] = s4_mk(S4_P16H(w1,w0), S4_P16H(w3,w2), S4_P16H(w5,w4), S4_P16H(w7,w6)); \
  Pl[SL] = s4_mk(S4_P16L(w1,w0), S4_P16L(w3,w2), S4_P16L(w5,w4), S4_P16L(w7,w6)); \
  Wp -= 32; }

#define S4_MM(ph,d,BH,BL) \
  acc[d] = __builtin_amdgcn_mfma_f32_16x16x32_bf16(Ph[((ph)+5+(d))%12], BH, acc[d], 0, 0, 0); \
  acc[d] = __builtin_amdgcn_mfma_f32_16x16x32_bf16(Pl[((ph)+5+(d))%12], BH, acc[d], 0, 0, 0); \
  acc[d] = __builtin_amdgcn_mfma_f32_16x16x32_bf16(Ph[((ph)+5+(d))%12], BL, acc[d], 0, 0, 0);

// B prefetch: clamp >2400 first (A=0 beyond seq end), then j<0 -> zeroed pad at 2432.
#define S4_PHASE(ph,BC,BN) { \
  S4_FILL(((ph)+4)%12); \
  int bn = j0 - 32; bn = bn > 2400 ? 2400 : bn; bn = bn < 0 ? 2432 : bn; \
  const char* bp = LB + ubo + 2*bn; \
  Bh##BN = *(const bf16x8*)bp; \
  Bl##BN = *(const bf16x8*)(bp + S4_ULO); \
  S4_MM(ph,0,Bh##BC,Bl##BC) S4_MM(ph,1,Bh##BC,Bl##BC) S4_MM(ph,2,Bh##BC,Bl##BC) S4_MM(ph,3,Bh##BC,Bl##BC) \
  S4_MM(ph,4,Bh##BC,Bl##BC) S4_MM(ph,5,Bh##BC,Bl##BC) S4_MM(ph,6,Bh##BC,Bl##BC) S4_MM(ph,7,Bh##BC,Bl##BC) \
  j0 -= 32; }

// One workgroup (8 waves, 2/SIMD for latency hiding) per h. 20 chains of 8 tiles
// (l spaced 32), (g,half) jointly LPT-balanced across waves (max 144 phases/wave),
// via a 12-slot rotating A-frag pipe (load once per K-step, shared by all 8 tiles).
// N dim = batch (8 real cols, lanes 8..15 duplicate rows; never written).
// Tail phases (j0<0) read the zeroed B pad -> contribute exactly 0.
// krev staging fused in: RV[e] = packed hi|lo of k[2704-e] (0 outside [0,2432)).
__global__ __launch_bounds__(512, 1) void k_s4m(const float* __restrict__ ksrc,
    const float* __restrict__ Dv, const float* __restrict__ u, float* __restrict__ y){
  extern __shared__ char LB[];
  ushort* UH = (ushort*)LB;
  ushort* UL = (ushort*)(LB + S4_ULO);
  u32* RV = (u32*)(LB + S4_REV);
  int h = blockIdx.x;
  int tid = threadIdx.x;
  // ---- stage u rows (b=0..7) as bf16 hi/lo planes ----
  for (int e = tid; e < 8 * 608; e += 512){
    int b = e / 608, c4 = e % 608;
    float4 v = *(const float4*)(u + ((size_t)b * 512 + h) * 2432 + c4 * 4);
    u32 p0 = packsplit(v.x), p1 = packsplit(v.y), p2 = packsplit(v.z), p3 = packsplit(v.w);
    uint2 hw, lw;
    hw.x = (p0 & 0xffffu) | (p1 << 16);
    hw.y = (p2 & 0xffffu) | (p3 << 16);
    lw.x = (p0 >> 16) | (p1 & 0xffff0000u);
    lw.y = (p2 >> 16) | (p3 & 0xffff0000u);
    *(uint2*)(LB + (size_t)b * (S4_SU*2) + c4 * 8) = hw;
    *(uint2*)(LB + S4_ULO + (size_t)b * (S4_SU*2) + c4 * 8) = lw;
  }
  // ---- zero the 32-element tail pad of every u row (both planes) ----
  if (tid < 256){
    int b = tid >> 5, i = tid & 31;
    UH[b * S4_SU + 2432 + i] = 0;
    UL[b * S4_SU + 2432 + i] = 0;
  }
  // ---- stage reversed-k: pack hi|lo in-kernel (fused k_krev) ----
  {
    const float* kg = ksrc + (size_t)h * 2432;
    for (int e = tid; e < 2856; e += 512){
      u32 v = 0;
      int t = 2704 - e;
      if (t >= 0 && t < 2432) v = packsplit(kg[t]);
      RV[e] = v;
    }
  }
  __syncthreads();

  int lane = tid & 63;
  int wid = __builtin_amdgcn_readfirstlane(tid >> 6);
  int m = lane & 15, qq = lane >> 4;
  int rl = 16 - m + 8 * qq;                       // rev element base (lane const)
  int ubo = (m & 7) * (S4_SU*2) + qq * 16;        // byte offset in u plane
  float dv = Dv[h];
  float* TSp = (float*)(LB + S4_TS + wid * 2304);
  // chains encoded g*2+half; LPT partition (units of 12 phases): {12,12,11,11,11,11,11,11}
  static const signed char GC[8][5] = {
    {19,10,-1,-1,-1},{18,12,-1,-1,-1},{17, 8,-1,-1,-1},{15, 7,-1,-1,-1},
    {16,11,-1,-1,-1},{14, 9,-1,-1,-1},{13, 6, 4,-1,-1},{ 5, 3, 2, 1, 0}};

  #pragma unroll 1
  for (int c = 0; c < 5; ++c){
    int gc = GC[wid][c];
    if (gc < 0) break;
    int g = gc >> 1, half = gc & 1;
    int Lb = 256 * g + (half << 4);
    int ltop = Lb + 224;
    int J0 = ((ltop + 15) >> 5) << 5;
    int W0 = 2688 - ltop + J0;
    int NS = (J0 >> 5) + 1;
    int nIt = (NS + 11) / 12;

    f32x4 acc[8];
    bf16x8 Ph[12], Pl[12];
    bf16x8 Bh0, Bl0, Bh1, Bl1;
    {
      f32x4 za = {0.f, 0.f, 0.f, 0.f};
      acc[0]=za; acc[1]=za; acc[2]=za; acc[3]=za; acc[4]=za; acc[5]=za; acc[6]=za; acc[7]=za;
      bf16x8 zz = s4_mk(0u,0u,0u,0u);
      Ph[5]=zz; Ph[6]=zz; Ph[7]=zz; Ph[8]=zz; Ph[9]=zz; Ph[10]=zz; Ph[11]=zz; Ph[4]=zz;
      Pl[5]=zz; Pl[6]=zz; Pl[7]=zz; Pl[8]=zz; Pl[9]=zz; Pl[10]=zz; Pl[11]=zz; Pl[4]=zz;
    }
    int Wp = W0;
    S4_FILL(0) S4_FILL(1) S4_FILL(2) S4_FILL(3)
    int j0 = J0;
    {
      int bj0 = j0 > 2400 ? 2400 : j0;
      const char* bp0 = LB + ubo + 2 * bj0;
      Bh0 = *(const bf16x8*)bp0;
      Bl0 = *(const bf16x8*)(bp0 + S4_ULO);
    }
    #pragma unroll 1
    for (int it = 0; it < nIt; ++it){
      S4_PHASE(0,0,1) S4_PHASE(1,1,0) S4_PHASE(2,0,1) S4_PHASE(3,1,0)
      S4_PHASE(4,0,1) S4_PHASE(5,1,0) S4_PHASE(6,0,1) S4_PHASE(7,1,0)
      S4_PHASE(8,0,1) S4_PHASE(9,1,0) S4_PHASE(10,0,1) S4_PHASE(11,1,0)
    }
    // ---- epilogue: per-wave LDS transpose + D skip, coalesced y write ----
    #pragma unroll
    for (int d = 0; d < 8; ++d){
      int ld = Lb + 32 * d;
      if (ld < 2432){
        if (m < 8){
          TSp[(qq*4+0)*9 + m] = acc[d][0];
          TSp[(qq*4+1)*9 + m] = acc[d][1];
          TSp[(qq*4+2)*9 + m] = acc[d][2];
          TSp[(qq*4+3)*9 + m] = acc[d][3];
        }
        __builtin_amdgcn_wave_barrier();
        #pragma unroll
        for (int p = 0; p < 2; ++p){
          int li = lane & 15, bb = (lane >> 4) + 4 * p;
          float v = TSp[li*9 + bb];
          int l = ld + li;
          float uv = bfu2f(UH[bb * S4_SU + l]) + bfu2f(UL[bb * S4_SU + l]);
          y[((size_t)bb * 512 + h) * 2432 + l] = v + dv * uv;
        }
        __builtin_amdgcn_wave_barrier();
      }
    }
  }
}

// ---------- final LayerNorm over last dim (200) with transpose
__global__ __launch_bounds__(256) void k_ln(const float* __restrict__ o2,
    const float* __restrict__ lw, const float* __restrict__ lb2, float* __restrict__ out){
  __shared__ float s1[256], s2[256];
  int row = blockIdx.x;
  int b = row / 2432, l = row % 2432;
  int t = threadIdx.x;
  float v = 0.f;
  if (t < 200) v = o2[((size_t)b * 200 + t) * LSEQ + l];
  s1[t] = v; s2[t] = v * v;
  __syncthreads();
  for (int off = 128; off > 0; off >>= 1){
    if (t < off){ s1[t] += s1[t + off]; s2[t] += s2[t + off]; }
    __syncthreads();
  }
  float m = s1[0] * 0.005f;
  float var = s2[0] * 0.005f - m * m;
  float istd = rsqrtf(var + 1e-5f);
  if (t < 200) out[(size_t)row * 200 + t] = (v - m) * istd * lw[t] + lb2[t];
}

extern "C" void kernel_launch(void* const* d_in, const int* in_sizes, int n_in,
                              void* d_out, int out_size, void* d_ws, size_t ws_size,
                              hipStream_t stream){
  const float* x     = (const float*)d_in[0];
  const float* pe_w  = (const float*)d_in[1];
  const float* pe_b  = (const float*)d_in[2];
  const float* pi0_w = (const float*)d_in[3];
  const float* pi0_b = (const float*)d_in[4];
  const float* gn0_w = (const float*)d_in[5];
  const float* gn0_b = (const float*)d_in[6];
  const float* pi1_w = (const float*)d_in[7];
  const float* pi1_b = (const float*)d_in[8];
  const float* gn1_w = (const float*)d_in[9];
  const float* gn1_b = (const float*)d_in[10];
  const float* pi2_w = (const float*)d_in[11];
  const float* pi2_b = (const float*)d_in[12];
  const float* gn2_w = (const float*)d_in[13];
  const float* gn2_b = (const float*)d_in[14];
  const float* spec_w= (const float*)d_in[15];
  const float* spec_b= (const float*)d_in[16];
  const float* ic_w  = (const float*)d_in[17];
  const float* ic_b  = (const float*)d_in[18];
  const float* blk_sn= (const float*)d_in[19];
  const float* blk_cw= (const float*)d_in[20];
  const float* blk_cb= (const float*)d_in[21];
  const float* blk_k = (const float*)d_in[22];
  const float* blk_D = (const float*)d_in[23];
  const float* blk_ow= (const float*)d_in[24];
  const float* blk_ob= (const float*)d_in[25];
  const float* blk_Wv= (const float*)d_in[26];
  const float* blk_bv= (const float*)d_in[27];
  const float* blk_Wo= (const float*)d_in[28];
  const float* blk_bo= (const float*)d_in[29];
  const float* blk_rw= (const float*)d_in[30];
  const float* blk_rb= (const float*)d_in[31];
  const float* blk_sw= (const float*)d_in[32];
  const float* blk_sb= (const float*)d_in[33];
  const float* fc_w  = (const float*)d_in[34];
  const float* fc_b  = (const float*)d_in[35];
  const float* zc_w  = (const float*)d_in[36];
  const float* zc_b  = (const float*)d_in[37];
  const float* ln_w  = (const float*)d_in[38];
  const float* ln_b  = (const float*)d_in[39];

  // allow >64KB dynamic LDS for k_s4m (host-side, graph-capture safe)
  static int s4m_attr = 0;
  if (!s4m_attr){
    hipFuncSetAttribute(reinterpret_cast<const void*>(k_s4m),
                        hipFuncAttributeMaxDynamicSharedMemorySize, S4_LDSZ);
    s4m_attr = 1;
  }

  float* Wsp = (float*)d_ws;
  const size_t NLL = (size_t)8 * 256 * 2432;    // 4,980,736 floats
  float* noise = Wsp;                 // [0,1)
  float* hxb   = Wsp + NLL;           // [1,2)
  float* skb   = Wsp + 2 * NLL;       // [2,3)
  float* ub    = Wsp + 3 * NLL;       // [3,5)  u / v / a / fc-out
  float* ysb   = Wsp + 5 * NLL;       // [5,7)  s4-out per s / ht / zc-out
  float* htb   = ysb;
  unsigned short* actT = (unsigned short*)(Wsp + 7 * NLL);   // [7,11) bf16 [b][l][2048]
  unsigned short* wB = (unsigned short*)(Wsp + 11 * NLL);
  unsigned short* owB = wB;                    // 6*1024*2048 = 12,582,912
  unsigned short* WvB = wB + 12582912;         // 1,572,864
  unsigned short* WoB = wB + 14155776;         // 1,572,864
  unsigned short* rwB = wB + 15728640;         // 393,216
  unsigned short* swB = wB + 16121856;         // 393,216
  unsigned short* icB = wB + 16515072;         // 57,344
  unsigned short* fcB = wB + 16572416;         // 65,536
  unsigned short* zcB = wB + 16637952;         // 51,200 -> end 16,689,152 ushorts
  float* rinv   = Wsp + 11 * NLL + 8344576;    // 19,456 floats
  float* gnstats= rinv + 19456;                // 80 floats
  u32* WpB = (u32*)(Wsp + 63152208);           // conv3 packed W: 393,216 dwords (old krev region)
  u32* XpT = (u32*)(Wsp + 7 * NLL);            // conv3 packed X: 4,980,736 dwords (actT region, dead then)

  // front-end aliases (regions dead at that point)
  float* p0 = ub;
  float* p1 = ysb;
  float* p2 = ub;
  float* pe = Wsp + 7 * NLL;          // actT region (floats), dead before first castT use
  float* spec = Wsp + 8 * NLL;
  float* peT = skb;                   // skb garbage OK (first sw gemm accf=0)
  float* hb = hxb;                    // overwritten later by memcpy noise->hxb

  const float SQ05 = 0.70710678118654752440f;
  const float SQ16 = 0.40824829046386301637f;

  // ---- weight casts (bf16) ----
  k_wcast_glu<<<49152,256,0,stream>>>(blk_ow, owB);
  k_wcast<<<(3072*512+255)/256,256,0,stream>>>(blk_Wv, WvB, 3072, 512, 512);
  k_wcast<<<(3072*512+255)/256,256,0,stream>>>(blk_Wo, WoB, 3072, 512, 512);
  k_wcast<<<(1536*256+255)/256,256,0,stream>>>(blk_rw, rwB, 1536, 256, 256);
  k_wcast<<<(1536*256+255)/256,256,0,stream>>>(blk_sw, swB, 1536, 256, 256);
  k_wcast<<<(256*224+255)/256,256,0,stream>>>(ic_w, icB, 256, 200, 224);
  k_wcast<<<(256*256+255)/256,256,0,stream>>>(fc_w, fcB, 256, 256, 256);
  k_wcast<<<(200*256+255)/256,256,0,stream>>>(zc_w, zcB, 200, 256, 256);

  // ---- PatchEmbedding ----
  k_pi0b<<<dim3(76,8), 256, 0, stream>>>(x, pi0_w, pi0_b, p0);
  k_gn_reduce<<<40,256,0,stream>>>(p0, gnstats);
  k_gn_apply<<<15200,256,0,stream>>>(p0, gnstats, gn0_w, gn0_b);
  k_pconv3b<<<dim3(76,8),256,0,stream>>>(p0, pi1_w, pi1_b, p1);
  k_gn_reduce<<<40,256,0,stream>>>(p1, gnstats);
  k_gn_apply<<<15200,256,0,stream>>>(p1, gnstats, gn1_w, gn1_b);
  k_pconv3b<<<dim3(76,8),256,0,stream>>>(p1, pi2_w, pi2_b, p2);
  k_gn_reduce<<<40,256,0,stream>>>(p2, gnstats);
  k_gn_apply<<<15200,256,0,stream>>>(p2, gnstats, gn2_w, gn2_b);
  k_pe_build<<<15200,256,0,stream>>>(p2, pe);
  k_spec<<<19456,256,0,stream>>>(x, spec);
  k_spec_mm<<<19456,256,0,stream>>>(spec, spec_w, spec_b, pe);
  k_trp<<<dim3(76,7,8),256,0,stream>>>(pe, peT);
  k_hbuild2<<<dim3(19,200,8),128,0,stream>>>(peT, pe_w, pe_b, hb);
  k_castT<<<dim3(76,7,8),256,0,stream>>>(hb, actT, 200, 224, 0);
  k_bgemm<<<dim3(19,2,8),256,0,stream>>>(icB, actT, ic_b, nullptr, nullptr, nullptr,
                                         noise, 256, 224, 1.f, 1.f, 1, 0);
  hipMemcpyAsync(hxb, noise, NLL * sizeof(float), hipMemcpyDeviceToDevice, stream);

  // ---- residual blocks ----
  for (int i = 0; i < 6; ++i){
    const float* sn = blk_sn + i * 256;
    const float* cw = blk_cw + (size_t)i * 512 * 768;
    const float* cb = blk_cb + i * 512;
    const float* ob = blk_ob + i * 1024;
    const float* bv = blk_bv + i * 512;
    const float* bo = blk_bo + i * 512;
    const float* rb = blk_rb + i * 256;
    const float* sb = blk_sb + i * 256;

    k_rmsr<<<76,256,0,stream>>>(hxb, rinv);
    // conv3 via MFMA: pack X (hx+noise, transposed) and W, then GEMM
    k_packT<<<dim3(76,8,8),256,0,stream>>>(hxb, noise, XpT);
    k_wpack3<<<1536,256,0,stream>>>(cw, WpB);
    k_conv3m<<<dim3(19,4,8),256,0,stream>>>(WpB, cb, XpT, ub);
    for (int s = 0; s < 4; ++s){
      const float* kw = blk_k + ((size_t)i * 4 + s) * 512 * 2432;
      const float* Dvp = blk_D + ((size_t)i * 4 + s) * 512;
      k_s4m<<<dim3(512),512,S4_LDSZ,stream>>>(kw, Dvp, ub, ysb);
      k_castT<<<dim3(76,16,8),256,0,stream>>>(ysb, actT, 512, 2048, s * 512);
    }
    // fused ow-GEMM + GLU -> ht (512 ch)
    k_bgemm<<<dim3(19,8,8),256,0,stream>>>(owB + (size_t)i*1024*2048, actT, ob,
                                           nullptr, nullptr, nullptr, htb,
                                           1024, 2048, 1.f, 1.f, 3, 0);
    k_castT<<<dim3(76,16,8),256,0,stream>>>(htb, actT, 512, 512, 0);
    k_bgemm<<<dim3(19,4,8),256,0,stream>>>(WvB + (size_t)i*512*512, actT, bv,
                                           nullptr, nullptr, nullptr, ub,
                                           512, 512, 1.f, 1.f, 0, 0);
    k_castT<<<dim3(76,16,8),256,0,stream>>>(ub, actT, 512, 512, 0);
    k_bgemm<<<dim3(19,4,8),256,0,stream>>>(WoB + (size_t)i*512*512, actT, bo,
                                           nullptr, nullptr, nullptr, ub,
                                           512, 512, 1.f, 1.f, 0, 0);
    k_gateT<<<dim3(76,8,8),256,0,stream>>>(htb, ub, actT);
    // rw-GEMM with fused RMS residual: hx = (sn*hx*rinv + rw@out + rb)*sqrt(0.5)
    k_bgemm<<<dim3(19,2,8),256,0,stream>>>(rwB + (size_t)i*256*256, actT, rb,
                                           hxb, sn, rinv, hxb,
                                           256, 256, 1.f, SQ05, 0, 0);
    k_bgemm<<<dim3(19,2,8),256,0,stream>>>(swB + (size_t)i*256*256, actT, sb,
                                           nullptr, nullptr, nullptr, skb,
                                           256, 256, 1.f, 1.f, 0, i==0?0:1);
  }

  // ---- tail ----
  k_castT<<<dim3(76,8,8),256,0,stream>>>(skb, actT, 256, 256, 0);
  k_bgemm<<<dim3(19,2,8),256,0,stream>>>(fcB, actT, fc_b, nullptr, nullptr, nullptr,
                                         ub, 256, 256, SQ16, 1.f, 1, 0);
  k_castT<<<dim3(76,8,8),256,0,stream>>>(ub, actT, 256, 256, 0);
  k_bgemm<<<dim3(19,2,8),256,0,stream>>>(zcB, actT, zc_b, nullptr, nullptr, nullptr,
                                         ysb, 200, 256, 1.f, 1.f, 0, 0);
  k_ln<<<19456,256,0,stream>>>(ysb, ln_w, ln_b, (float*)d_out);
}